// Round 1
// baseline (20970.288 us; speedup 1.0000x reference)
//
#include <hip/hip_runtime.h>
#include <math.h>

// ---------------------------------------------------------------------------
// HRSNN: LSTM(H=10) over B*T=51200 steps  ->  spiking-neuron modules (LIF
// scans) -> batchnorm + classifier head.  Everything sequential runs as
// single-wave scan kernels with register prefetch rings; everything pointwise
// in t runs as wide elementwise kernels.
// ---------------------------------------------------------------------------

namespace {
constexpr int TT = 51200;  // B*T
// taus (double-precision values, rounded to f32 at compile time)
constexpr double TAU1d = 1.2231301601484298;  // exp(-1.5)+1
constexpr double TAU2d = 1.3678794411714423;  // exp(-1.0)+1  (== TAU4)
constexpr double TAU3d = 1.4493289641172216;  // exp(-0.8)+1

// workspace layout (float offsets). HL overlays PRE+HSEQ (dead by then).
constexpr size_t OFF_PRE   = 0;         // 51200*40   K1..K2
constexpr size_t OFF_HL    = 0;         // 51200*60   K4..K5, K8..K9
constexpr size_t OFF_HSEQ  = 2048000;   // 51200*10   K2..K3
constexpr size_t OFF_XIN1  = 3072000;   // 51200*20   K3..K7
constexpr size_t OFF_C     = 4096000;   // 51200*20
constexpr size_t OFF_S4    = 5120000;   // 51200*20
constexpr size_t OFF_XIN2  = 6144000;   // 51200*20   K7..K11
constexpr size_t OFF_OUT2  = 7168000;   // 51200*10
constexpr size_t OFF_OUT3  = 7680000;   // 512*100*10
constexpr size_t OFF_FUSED = 8192000;   // 512*200
constexpr size_t OFF_STATS = 8294400;   // 512*2 doubles (byte off divisible by 8)
}  // namespace

__device__ __forceinline__ float rcp_nr(float d) {
  float r = __builtin_amdgcn_rcpf(d);
  return r * (2.0f - d * r);  // one Newton step: ~1ulp
}
__device__ __forceinline__ float fsig(float x) {
  return rcp_nr(1.0f + __expf(-x));
}
__device__ __forceinline__ float ftanh(float x) {
  return 1.0f - 2.0f * rcp_nr(__expf(2.0f * x) + 1.0f);
}

// K1: pregate[t][l] = sum_c x[b][c][tt]*wih[l][c] + bih[l] + bhh[l]
__global__ void __launch_bounds__(64) k_pregate(const float* __restrict__ x,
                                                const float* __restrict__ wih,
                                                const float* __restrict__ bih,
                                                const float* __restrict__ bhh,
                                                float* __restrict__ pre) {
  __shared__ float xs[64];
  const int t = blockIdx.x;
  const int b = t / 100;
  const int tt = t - b * 100;
  const int lane = threadIdx.x;
  xs[lane] = x[b * 6400 + lane * 100 + tt];
  __syncthreads();
  if (lane < 40) {
    float acc = bih[lane] + bhh[lane];
    const float* w = wih + lane * 64;
#pragma unroll
    for (int c = 0; c < 64; ++c) acc = fmaf(xs[c], w[c], acc);
    pre[t * 40 + lane] = acc;
  }
}

// K2: sequential LSTM scan, one wave. Lane l<40 owns gate l; lanes gather
// their (i,f,g,o) via bpermute; h broadcast to SGPRs via readlane.
__global__ void __launch_bounds__(64) k_lstm(const float* __restrict__ pre,
                                             const float* __restrict__ whh,
                                             float* __restrict__ hseq) {
  const int lane = threadIdx.x;
  const int l = lane < 40 ? lane : 0;
  float wh[10];
#pragma unroll
  for (int j = 0; j < 10; ++j) wh[j] = whh[l * 10 + j];
  const int jm = lane % 10;  // every lane mirrors one j -> no junk lanes
  float cst = 0.0f;
  float h[10];
#pragma unroll
  for (int j = 0; j < 10; ++j) h[j] = 0.0f;
  float pbuf[4];  // 4-deep global prefetch ring
#pragma unroll
  for (int i = 0; i < 4; ++i) pbuf[i] = pre[i * 40 + l];
#pragma unroll 4
  for (int t = 0; t < TT; ++t) {
    float g = pbuf[t & 3];
    const int tn = t + 4;
    pbuf[t & 3] = pre[(tn < TT ? tn : 0) * 40 + l];
#pragma unroll
    for (int j = 0; j < 10; ++j) g = fmaf(h[j], wh[j], g);
    const float gi = __shfl(g, jm);
    const float gf = __shfl(g, jm + 10);
    const float gg = __shfl(g, jm + 20);
    const float go = __shfl(g, jm + 30);
    cst = fsig(gf) * cst + fsig(gi) * ftanh(gg);
    const float hn = fsig(go) * ftanh(cst);
    if (lane < 10) hseq[t * 10 + lane] = hn;
#pragma unroll
    for (int j = 0; j < 10; ++j)
      h[j] = __uint_as_float(__builtin_amdgcn_readlane(__float_as_uint(hn), j));
  }
}

// K3: conv_out = hseq @ sc_w[:,0,:].T + sc_b   (pointwise in t)
__global__ void __launch_bounds__(256) k_sconv(const float* __restrict__ hseq,
                                               const float* __restrict__ sw,
                                               const float* __restrict__ sb,
                                               float* __restrict__ xin) {
  const int i = blockIdx.x * 256 + threadIdx.x;
  if (i >= TT * 20) return;
  const int t = i / 20;
  const int o = i - t * 20;
  const float* hp = hseq + t * 10;
  const float* wp = sw + o * 10;
  float acc = sb[o];
#pragma unroll
  for (int j = 0; j < 10; ++j) acc = fmaf(hp[j], wp[j], acc);
  xin[i] = acc;
}

// K4/K8: 60 independent LIF chains (f<20, k<3), one wave, 32-deep prefetch.
__global__ void __launch_bounds__(64) k_lif3(const float* __restrict__ xin,
                                             float* __restrict__ hl) {
  const int lane = threadIdx.x;
  const int cid = lane < 60 ? lane : 0;
  const int f = cid / 3;
  const int k = cid - f * 3;
  const float tau = (k == 0) ? (float)TAU1d : (k == 1) ? (float)TAU2d : (float)TAU3d;
  const float rt = 1.0f / tau;
  const float th = (k == 0) ? 0.14f : (k == 1) ? 0.08f : 0.06f;
  float v = 0.0f;
  float xb[32];
#pragma unroll
  for (int i = 0; i < 32; ++i) xb[i] = xin[i * 20 + f];
#pragma unroll 32
  for (int t = 0; t < TT; ++t) {
    const float x = xb[t & 31];
    const int tn = t + 32;
    xb[t & 31] = xin[(tn < TT ? tn : 0) * 20 + f];
    v = fmaf(x - v, rt, v);
    const float sp = (v - th >= 0.0f) ? 1.0f : 0.0f;
    if (lane < 60) hl[t * 60 + lane] = sp;
    v = (sp != 0.0f) ? 0.0f : v;
  }
}

// K5/K9: c[t][o] = sum_{f,k} hl[t][f][k]*conv_w[o][f][k] + conv_b[o]
__global__ void __launch_bounds__(256) k_conv60(const float* __restrict__ hl,
                                                const float* __restrict__ cw,
                                                const float* __restrict__ cb,
                                                float* __restrict__ cout) {
  const int i = blockIdx.x * 256 + threadIdx.x;
  if (i >= TT * 20) return;
  const int t = i / 20;
  const int o = i - t * 20;
  const float* hp = hl + t * 60;
  const float* wp = cw + o * 60;
  float acc = cb[o];
#pragma unroll
  for (int d = 0; d < 60; ++d) acc = fmaf(hp[d], wp[d], acc);
  cout[i] = acc;
}

// K6/K10: 20 independent LIF chains (tau4, theta=0.08), one wave.
__global__ void __launch_bounds__(64) k_lifseq(const float* __restrict__ xin,
                                               float* __restrict__ sp_out) {
  const int lane = threadIdx.x;
  const int f = lane < 20 ? lane : 0;
  const float rt = 1.0f / (float)TAU2d;
  float v = 0.0f;
  float xb[32];
#pragma unroll
  for (int i = 0; i < 32; ++i) xb[i] = xin[i * 20 + f];
#pragma unroll 32
  for (int t = 0; t < TT; ++t) {
    const float x = xb[t & 31];
    const int tn = t + 32;
    xb[t & 31] = xin[(tn < TT ? tn : 0) * 20 + f];
    v = fmaf(x - v, rt, v);
    const float sp = (v - 0.08f >= 0.0f) ? 1.0f : 0.0f;
    if (lane < 20) sp_out[t * 20 + lane] = sp;
    v = (sp != 0.0f) ? 0.0f : v;
  }
}

// K7/K11: out = s4@fc_w.T + fc_b + xin@skip_w[:,:,0].T + skip_b
template <int O>
__global__ void __launch_bounds__(256) k_fcskip(const float* __restrict__ s4,
                                                const float* __restrict__ xin,
                                                const float* __restrict__ fw,
                                                const float* __restrict__ fb,
                                                const float* __restrict__ sw,
                                                const float* __restrict__ sb,
                                                float* __restrict__ outp) {
  const int i = blockIdx.x * 256 + threadIdx.x;
  if (i >= TT * O) return;
  const int t = i / O;
  const int o = i - t * O;
  const float* s = s4 + t * 20;
  const float* xi = xin + t * 20;
  const float* fwp = fw + o * 20;
  const float* swp = sw + o * 20;
  float acc = fb[o] + sb[o];
#pragma unroll
  for (int j = 0; j < 20; ++j) acc = fmaf(s[j], fwp[j], fmaf(xi[j], swp[j], acc));
  outp[i] = acc;
}

// K12: final LIF over batch axis: 1000 chains (tt,f), 512 steps each.
__global__ void __launch_bounds__(1024) k_flif(const float* __restrict__ out2,
                                               float* __restrict__ out3) {
  const int tid = threadIdx.x;
  if (tid >= 1000) return;
  const float rt = 1.0f / (float)TAU2d;
  float v = 0.0f;
  float xb[8];
#pragma unroll
  for (int i = 0; i < 8; ++i) xb[i] = out2[i * 1000 + tid];
#pragma unroll 8
  for (int b = 0; b < 512; ++b) {
    const float x = xb[b & 7];
    const int nb = b + 8;
    xb[b & 7] = out2[(nb < 512 ? nb : 0) * 1000 + tid];
    v = fmaf(x - v, rt, v);
    const float sp = (v - 0.08f >= 0.0f) ? 1.0f : 0.0f;
    out3[b * 1000 + tid] = sp;
    v = (sp != 0.0f) ? 0.0f : v;
  }
}

// K13: dp -> avg -> fused; per-block (per-b) partial sum/sumsq in double.
__global__ void __launch_bounds__(256) k_fused(const float* __restrict__ out3,
                                               float* __restrict__ fused,
                                               double* __restrict__ stats) {
  __shared__ float dp_s[200];
  __shared__ float avg_s[20];
  __shared__ double red_s[8];
  const int b = blockIdx.x;
  const int tid = threadIdx.x;
  if (tid < 200) {
    const int f = tid / 20;
    const int seg = tid - f * 20;
    const float* base = out3 + b * 1000 + seg * 50 + f;  // tt = seg*5+q, +f
    dp_s[tid] = ((base[30] + base[40]) - (base[0] + base[10])) * 0.5f;
  }
  __syncthreads();
  if (tid < 20) {
    float s = 0.0f;
#pragma unroll
    for (int f = 0; f < 10; ++f) s += dp_s[f * 20 + tid];
    avg_s[tid] = s / 10.0f;
  }
  __syncthreads();
  float val = 0.0f;
  if (tid < 200) {
    val = dp_s[tid] * avg_s[tid % 20];
    fused[b * 200 + tid] = val;
  }
  double sv = (double)val, sq = (double)val * (double)val;
#pragma unroll
  for (int off = 32; off > 0; off >>= 1) {
    sv += __shfl_down(sv, off);
    sq += __shfl_down(sq, off);
  }
  const int wid = tid >> 6;
  if ((tid & 63) == 0) { red_s[wid * 2] = sv; red_s[wid * 2 + 1] = sq; }
  __syncthreads();
  if (tid == 0) {
    double S = 0.0, Q = 0.0;
#pragma unroll
    for (int w = 0; w < 4; ++w) { S += red_s[w * 2]; Q += red_s[w * 2 + 1]; }
    stats[b * 2] = S;
    stats[b * 2 + 1] = Q;
  }
}

// K14: reduce stats -> mean/var -> bn -> logits -> log_softmax. One block.
__global__ void __launch_bounds__(1024) k_head(const float* __restrict__ fused,
                                               const double* __restrict__ stats,
                                               const float* __restrict__ gamma,
                                               const float* __restrict__ beta,
                                               const float* __restrict__ clsw,
                                               const float* __restrict__ clsb,
                                               float* __restrict__ out) {
  __shared__ double redS[16], redQ[16];
  __shared__ float cls_s[600];
  __shared__ float cb_s[3];
  __shared__ float mr_s[2];
  const int tid = threadIdx.x;
  if (tid < 600) cls_s[tid] = clsw[tid];
  if (tid < 3) cb_s[tid] = clsb[tid];
  double s = 0.0, q = 0.0;
  if (tid < 512) { s = stats[2 * tid]; q = stats[2 * tid + 1]; }
#pragma unroll
  for (int off = 32; off > 0; off >>= 1) {
    s += __shfl_down(s, off);
    q += __shfl_down(q, off);
  }
  const int wid = tid >> 6;
  if ((tid & 63) == 0) { redS[wid] = s; redQ[wid] = q; }
  __syncthreads();
  if (tid == 0) {
    double S = 0.0, Q = 0.0;
#pragma unroll
    for (int w = 0; w < 16; ++w) { S += redS[w]; Q += redQ[w]; }
    const double mean = S / 102400.0;
    const double var = Q / 102400.0 - mean * mean;
    mr_s[0] = (float)mean;
    mr_s[1] = (float)(1.0 / sqrt(var + 1e-5));
  }
  __syncthreads();
  if (tid < 512) {
    const float mean = mr_s[0], rsig = mr_s[1];
    const float ga = gamma[0], be = beta[0];
    const float* fr = fused + tid * 200;
    float l0 = cb_s[0], l1 = cb_s[1], l2 = cb_s[2];
    for (int j = 0; j < 200; ++j) {
      const float bn = (fr[j] - mean) * rsig * ga + be;
      l0 = fmaf(bn, cls_s[j], l0);
      l1 = fmaf(bn, cls_s[200 + j], l1);
      l2 = fmaf(bn, cls_s[400 + j], l2);
    }
    const float m = fmaxf(l0, fmaxf(l1, l2));
    const float lse = m + logf(expf(l0 - m) + expf(l1 - m) + expf(l2 - m));
    out[tid * 3 + 0] = l0 - lse;
    out[tid * 3 + 1] = l1 - lse;
    out[tid * 3 + 2] = l2 - lse;
  }
}

extern "C" void kernel_launch(void* const* d_in, const int* in_sizes, int n_in,
                              void* d_out, int out_size, void* d_ws, size_t ws_size,
                              hipStream_t stream) {
  (void)in_sizes; (void)n_in; (void)out_size; (void)ws_size;
  const float* x     = (const float*)d_in[0];
  const float* wih   = (const float*)d_in[1];
  const float* whh   = (const float*)d_in[2];
  const float* bih   = (const float*)d_in[3];
  const float* bhh   = (const float*)d_in[4];
  const float* sc_w  = (const float*)d_in[5];
  const float* sc_b  = (const float*)d_in[6];
  const float* c1w   = (const float*)d_in[7];
  const float* c1b   = (const float*)d_in[8];
  const float* f1w   = (const float*)d_in[9];
  const float* f1b   = (const float*)d_in[10];
  const float* k1w   = (const float*)d_in[11];
  const float* k1b   = (const float*)d_in[12];
  const float* c2w   = (const float*)d_in[13];
  const float* c2b   = (const float*)d_in[14];
  const float* f2w   = (const float*)d_in[15];
  const float* f2b   = (const float*)d_in[16];
  const float* k2w   = (const float*)d_in[17];
  const float* k2b   = (const float*)d_in[18];
  const float* gamma = (const float*)d_in[19];
  const float* beta  = (const float*)d_in[20];
  const float* clsw  = (const float*)d_in[21];
  const float* clsb  = (const float*)d_in[22];
  float* out = (float*)d_out;
  float* ws = (float*)d_ws;

  float* pre   = ws + OFF_PRE;
  float* hl    = ws + OFF_HL;
  float* hseq  = ws + OFF_HSEQ;
  float* xin1  = ws + OFF_XIN1;
  float* cbuf  = ws + OFF_C;
  float* s4    = ws + OFF_S4;
  float* xin2  = ws + OFF_XIN2;
  float* out2  = ws + OFF_OUT2;
  float* out3  = ws + OFF_OUT3;
  float* fused = ws + OFF_FUSED;
  double* stats = (double*)(ws + OFF_STATS);

  k_pregate<<<TT, 64, 0, stream>>>(x, wih, bih, bhh, pre);
  k_lstm<<<1, 64, 0, stream>>>(pre, whh, hseq);
  k_sconv<<<(TT * 20 + 255) / 256, 256, 0, stream>>>(hseq, sc_w, sc_b, xin1);
  // hr module 1
  k_lif3<<<1, 64, 0, stream>>>(xin1, hl);
  k_conv60<<<(TT * 20 + 255) / 256, 256, 0, stream>>>(hl, c1w, c1b, cbuf);
  k_lifseq<<<1, 64, 0, stream>>>(cbuf, s4);
  k_fcskip<20><<<(TT * 20 + 255) / 256, 256, 0, stream>>>(s4, xin1, f1w, f1b, k1w, k1b, xin2);
  // hr module 2
  k_lif3<<<1, 64, 0, stream>>>(xin2, hl);
  k_conv60<<<(TT * 20 + 255) / 256, 256, 0, stream>>>(hl, c2w, c2b, cbuf);
  k_lifseq<<<1, 64, 0, stream>>>(cbuf, s4);
  k_fcskip<10><<<(TT * 10 + 255) / 256, 256, 0, stream>>>(s4, xin2, f2w, f2b, k2w, k2b, out2);
  // final LIF over batch axis + head
  k_flif<<<1, 1024, 0, stream>>>(out2, out3);
  k_fused<<<512, 256, 0, stream>>>(out3, fused, stats);
  k_head<<<1, 1024, 0, stream>>>(fused, stats, gamma, beta, clsw, clsb, out);
}

// Round 2
// 17016.489 us; speedup vs baseline: 1.2324x; 1.2324x over previous
//
#include <hip/hip_runtime.h>
#include <math.h>

// ---------------------------------------------------------------------------
// HRSNN: LSTM(H=10) over B*T=51200 steps  ->  spiking-neuron modules (LIF
// scans) -> batchnorm + classifier head.  Sequential parts run as single-wave
// scan kernels with register prefetch rings; pointwise-in-t parts run wide.
//
// R2: LSTM redesigned — per-lane single activation (sigmoid/tanh selected by
// lane) + post-activation bpermute gather; prefetch rings drop wrap-selects
// (over-read into dead workspace). Formulas kept bitwise identical to R1.
// ---------------------------------------------------------------------------

namespace {
constexpr int TT = 51200;  // B*T
constexpr double TAU1d = 1.2231301601484298;  // exp(-1.5)+1
constexpr double TAU2d = 1.3678794411714423;  // exp(-1.0)+1  (== TAU4)
constexpr double TAU3d = 1.4493289641172216;  // exp(-0.8)+1

// workspace layout (float offsets). HL overlays PRE+HSEQ (dead by then).
constexpr size_t OFF_PRE   = 0;         // 51200*40 (+320 over-read pad)
constexpr size_t OFF_HL    = 0;         // 51200*60
constexpr size_t OFF_HSEQ  = 2048320;   // 51200*10
constexpr size_t OFF_XIN1  = 3072000;   // 51200*20
constexpr size_t OFF_C     = 4096000;   // 51200*20
constexpr size_t OFF_S4    = 5120000;   // 51200*20
constexpr size_t OFF_XIN2  = 6144000;   // 51200*20
constexpr size_t OFF_OUT2  = 7168000;   // 51200*10
constexpr size_t OFF_OUT3  = 7680000;   // 512*100*10
constexpr size_t OFF_FUSED = 8192000;   // 512*200
constexpr size_t OFF_STATS = 8294400;   // 512*2 doubles
}  // namespace

__device__ __forceinline__ float rcp_nr(float d) {
  float r = __builtin_amdgcn_rcpf(d);
  return r * (2.0f - d * r);  // one Newton step: ~1ulp
}

// K1: pregate[t][l] = sum_c x[b][c][tt]*wih[l][c] + bih[l] + bhh[l]
__global__ void __launch_bounds__(64) k_pregate(const float* __restrict__ x,
                                                const float* __restrict__ wih,
                                                const float* __restrict__ bih,
                                                const float* __restrict__ bhh,
                                                float* __restrict__ pre) {
  __shared__ float xs[64];
  const int t = blockIdx.x;
  const int b = t / 100;
  const int tt = t - b * 100;
  const int lane = threadIdx.x;
  xs[lane] = x[b * 6400 + lane * 100 + tt];
  __syncthreads();
  if (lane < 40) {
    float acc = bih[lane] + bhh[lane];
    const float* w = wih + lane * 64;
#pragma unroll
    for (int c = 0; c < 64; ++c) acc = fmaf(xs[c], w[c], acc);
    pre[t * 40 + lane] = acc;
  }
}

// K2: sequential LSTM scan, one wave.
// Lane l<40 owns gate l (i:0-9 f:10-19 g:20-29 o:30-39). Each lane applies
// ITS OWN activation (sigmoid or tanh, selected per-lane — one exp+rcp),
// then all lanes gather the four activated gates for unit jm=lane%10 via
// bpermute. h broadcast to SGPRs via readlane.
__global__ void __launch_bounds__(64) k_lstm(const float* __restrict__ pre,
                                             const float* __restrict__ whh,
                                             float* __restrict__ hseq) {
  const int lane = threadIdx.x;
  const int l = lane < 40 ? lane : 0;
  float wh[10];
#pragma unroll
  for (int j = 0; j < 10; ++j) wh[j] = whh[l * 10 + j];
  const int jm = lane % 10;
  const bool is_g = (l >= 20) & (l < 30);
  const float sel = is_g ? 2.0f : -1.0f;  // exp(sel*x): tanh uses exp(2x), sig exp(-x)
  float cst = 0.0f;
  float h[10];
#pragma unroll
  for (int j = 0; j < 10; ++j) h[j] = 0.0f;
  float pbuf[8];  // 8-deep global prefetch ring (over-reads 320 pad floats)
#pragma unroll
  for (int i = 0; i < 8; ++i) pbuf[i] = pre[i * 40 + l];
#pragma unroll 8
  for (int t = 0; t < TT; ++t) {
    float g = pbuf[t & 7];
    pbuf[t & 7] = pre[(t + 8) * 40 + l];
#pragma unroll
    for (int j = 0; j < 10; ++j) g = fmaf(h[j], wh[j], g);
    // per-lane activation (bitwise-identical formulas to R1's fsig/ftanh)
    const float e = __expf(sel * g);
    const float r = rcp_nr(1.0f + e);
    const float act = is_g ? (1.0f - 2.0f * r) : r;
    const float ai = __shfl(act, jm);
    const float af = __shfl(act, jm + 10);
    const float ag = __shfl(act, jm + 20);
    const float ao = __shfl(act, jm + 30);
    cst = af * cst + ai * ag;
    const float hn = ao * (1.0f - 2.0f * rcp_nr(__expf(2.0f * cst) + 1.0f));
    if (lane < 10) hseq[t * 10 + lane] = hn;
#pragma unroll
    for (int j = 0; j < 10; ++j)
      h[j] = __uint_as_float(__builtin_amdgcn_readlane(__float_as_uint(hn), j));
  }
}

// K3: conv_out = hseq @ sc_w[:,0,:].T + sc_b   (pointwise in t)
__global__ void __launch_bounds__(256) k_sconv(const float* __restrict__ hseq,
                                               const float* __restrict__ sw,
                                               const float* __restrict__ sb,
                                               float* __restrict__ xin) {
  const int i = blockIdx.x * 256 + threadIdx.x;
  if (i >= TT * 20) return;
  const int t = i / 20;
  const int o = i - t * 20;
  const float* hp = hseq + t * 10;
  const float* wp = sw + o * 10;
  float acc = sb[o];
#pragma unroll
  for (int j = 0; j < 10; ++j) acc = fmaf(hp[j], wp[j], acc);
  xin[i] = acc;
}

// K4/K8: 60 independent LIF chains (f<20, k<3), one wave, 32-deep prefetch.
__global__ void __launch_bounds__(64) k_lif3(const float* __restrict__ xin,
                                             float* __restrict__ hl) {
  const int lane = threadIdx.x;
  const int cid = lane < 60 ? lane : 0;
  const int f = cid / 3;
  const int k = cid - f * 3;
  const float tau = (k == 0) ? (float)TAU1d : (k == 1) ? (float)TAU2d : (float)TAU3d;
  const float rt = 1.0f / tau;
  const float th = (k == 0) ? 0.14f : (k == 1) ? 0.08f : 0.06f;
  float v = 0.0f;
  float xb[32];
#pragma unroll
  for (int i = 0; i < 32; ++i) xb[i] = xin[i * 20 + f];
#pragma unroll 32
  for (int t = 0; t < TT; ++t) {
    const float x = xb[t & 31];
    xb[t & 31] = xin[(t + 32) * 20 + f];  // over-reads 640 floats past end
    v = fmaf(x - v, rt, v);
    const float sp = (v - th >= 0.0f) ? 1.0f : 0.0f;
    if (lane < 60) hl[t * 60 + lane] = sp;
    v = (sp != 0.0f) ? 0.0f : v;
  }
}

// K5/K9: c[t][o] = sum_{f,k} hl[t][f][k]*conv_w[o][f][k] + conv_b[o]
__global__ void __launch_bounds__(256) k_conv60(const float* __restrict__ hl,
                                                const float* __restrict__ cw,
                                                const float* __restrict__ cb,
                                                float* __restrict__ cout) {
  const int i = blockIdx.x * 256 + threadIdx.x;
  if (i >= TT * 20) return;
  const int t = i / 20;
  const int o = i - t * 20;
  const float* hp = hl + t * 60;
  const float* wp = cw + o * 60;
  float acc = cb[o];
#pragma unroll
  for (int d = 0; d < 60; ++d) acc = fmaf(hp[d], wp[d], acc);
  cout[i] = acc;
}

// K6/K10: 20 independent LIF chains (tau4, theta=0.08), one wave.
__global__ void __launch_bounds__(64) k_lifseq(const float* __restrict__ xin,
                                               float* __restrict__ sp_out) {
  const int lane = threadIdx.x;
  const int f = lane < 20 ? lane : 0;
  const float rt = 1.0f / (float)TAU2d;
  float v = 0.0f;
  float xb[32];
#pragma unroll
  for (int i = 0; i < 32; ++i) xb[i] = xin[i * 20 + f];
#pragma unroll 32
  for (int t = 0; t < TT; ++t) {
    const float x = xb[t & 31];
    xb[t & 31] = xin[(t + 32) * 20 + f];  // over-reads past end (dead pad)
    v = fmaf(x - v, rt, v);
    const float sp = (v - 0.08f >= 0.0f) ? 1.0f : 0.0f;
    if (lane < 20) sp_out[t * 20 + lane] = sp;
    v = (sp != 0.0f) ? 0.0f : v;
  }
}

// K7/K11: out = s4@fc_w.T + fc_b + xin@skip_w[:,:,0].T + skip_b
template <int O>
__global__ void __launch_bounds__(256) k_fcskip(const float* __restrict__ s4,
                                                const float* __restrict__ xin,
                                                const float* __restrict__ fw,
                                                const float* __restrict__ fb,
                                                const float* __restrict__ sw,
                                                const float* __restrict__ sb,
                                                float* __restrict__ outp) {
  const int i = blockIdx.x * 256 + threadIdx.x;
  if (i >= TT * O) return;
  const int t = i / O;
  const int o = i - t * O;
  const float* s = s4 + t * 20;
  const float* xi = xin + t * 20;
  const float* fwp = fw + o * 20;
  const float* swp = sw + o * 20;
  float acc = fb[o] + sb[o];
#pragma unroll
  for (int j = 0; j < 20; ++j) acc = fmaf(s[j], fwp[j], fmaf(xi[j], swp[j], acc));
  outp[i] = acc;
}

// K12: final LIF over batch axis: 1000 chains (tt,f), 512 steps each.
__global__ void __launch_bounds__(1024) k_flif(const float* __restrict__ out2,
                                               float* __restrict__ out3) {
  const int tid = threadIdx.x;
  if (tid >= 1000) return;
  const float rt = 1.0f / (float)TAU2d;
  float v = 0.0f;
  float xb[8];
#pragma unroll
  for (int i = 0; i < 8; ++i) xb[i] = out2[i * 1000 + tid];
#pragma unroll 8
  for (int b = 0; b < 512; ++b) {
    const float x = xb[b & 7];
    xb[b & 7] = out2[(b + 8) * 1000 + tid];  // over-reads into out3 (dead)
    v = fmaf(x - v, rt, v);
    const float sp = (v - 0.08f >= 0.0f) ? 1.0f : 0.0f;
    out3[b * 1000 + tid] = sp;
    v = (sp != 0.0f) ? 0.0f : v;
  }
}

// K13: dp -> avg -> fused; per-block (per-b) partial sum/sumsq in double.
__global__ void __launch_bounds__(256) k_fused(const float* __restrict__ out3,
                                               float* __restrict__ fused,
                                               double* __restrict__ stats) {
  __shared__ float dp_s[200];
  __shared__ float avg_s[20];
  __shared__ double red_s[8];
  const int b = blockIdx.x;
  const int tid = threadIdx.x;
  if (tid < 200) {
    const int f = tid / 20;
    const int seg = tid - f * 20;
    const float* base = out3 + b * 1000 + seg * 50 + f;
    dp_s[tid] = ((base[30] + base[40]) - (base[0] + base[10])) * 0.5f;
  }
  __syncthreads();
  if (tid < 20) {
    float s = 0.0f;
#pragma unroll
    for (int f = 0; f < 10; ++f) s += dp_s[f * 20 + tid];
    avg_s[tid] = s / 10.0f;
  }
  __syncthreads();
  float val = 0.0f;
  if (tid < 200) {
    val = dp_s[tid] * avg_s[tid % 20];
    fused[b * 200 + tid] = val;
  }
  double sv = (double)val, sq = (double)val * (double)val;
#pragma unroll
  for (int off = 32; off > 0; off >>= 1) {
    sv += __shfl_down(sv, off);
    sq += __shfl_down(sq, off);
  }
  const int wid = tid >> 6;
  if ((tid & 63) == 0) { red_s[wid * 2] = sv; red_s[wid * 2 + 1] = sq; }
  __syncthreads();
  if (tid == 0) {
    double S = 0.0, Q = 0.0;
#pragma unroll
    for (int w = 0; w < 4; ++w) { S += red_s[w * 2]; Q += red_s[w * 2 + 1]; }
    stats[b * 2] = S;
    stats[b * 2 + 1] = Q;
  }
}

// K14: reduce stats -> mean/var -> bn -> logits -> log_softmax. One block.
__global__ void __launch_bounds__(1024) k_head(const float* __restrict__ fused,
                                               const double* __restrict__ stats,
                                               const float* __restrict__ gamma,
                                               const float* __restrict__ beta,
                                               const float* __restrict__ clsw,
                                               const float* __restrict__ clsb,
                                               float* __restrict__ out) {
  __shared__ double redS[16], redQ[16];
  __shared__ float cls_s[600];
  __shared__ float cb_s[3];
  __shared__ float mr_s[2];
  const int tid = threadIdx.x;
  if (tid < 600) cls_s[tid] = clsw[tid];
  if (tid < 3) cb_s[tid] = clsb[tid];
  double s = 0.0, q = 0.0;
  if (tid < 512) { s = stats[2 * tid]; q = stats[2 * tid + 1]; }
#pragma unroll
  for (int off = 32; off > 0; off >>= 1) {
    s += __shfl_down(s, off);
    q += __shfl_down(q, off);
  }
  const int wid = tid >> 6;
  if ((tid & 63) == 0) { redS[wid] = s; redQ[wid] = q; }
  __syncthreads();
  if (tid == 0) {
    double S = 0.0, Q = 0.0;
#pragma unroll
    for (int w = 0; w < 16; ++w) { S += redS[w]; Q += redQ[w]; }
    const double mean = S / 102400.0;
    const double var = Q / 102400.0 - mean * mean;
    mr_s[0] = (float)mean;
    mr_s[1] = (float)(1.0 / sqrt(var + 1e-5));
  }
  __syncthreads();
  if (tid < 512) {
    const float mean = mr_s[0], rsig = mr_s[1];
    const float ga = gamma[0], be = beta[0];
    const float* fr = fused + tid * 200;
    float l0 = cb_s[0], l1 = cb_s[1], l2 = cb_s[2];
    for (int j = 0; j < 200; ++j) {
      const float bn = (fr[j] - mean) * rsig * ga + be;
      l0 = fmaf(bn, cls_s[j], l0);
      l1 = fmaf(bn, cls_s[200 + j], l1);
      l2 = fmaf(bn, cls_s[400 + j], l2);
    }
    const float m = fmaxf(l0, fmaxf(l1, l2));
    const float lse = m + logf(expf(l0 - m) + expf(l1 - m) + expf(l2 - m));
    out[tid * 3 + 0] = l0 - lse;
    out[tid * 3 + 1] = l1 - lse;
    out[tid * 3 + 2] = l2 - lse;
  }
}

extern "C" void kernel_launch(void* const* d_in, const int* in_sizes, int n_in,
                              void* d_out, int out_size, void* d_ws, size_t ws_size,
                              hipStream_t stream) {
  (void)in_sizes; (void)n_in; (void)out_size; (void)ws_size;
  const float* x     = (const float*)d_in[0];
  const float* wih   = (const float*)d_in[1];
  const float* whh   = (const float*)d_in[2];
  const float* bih   = (const float*)d_in[3];
  const float* bhh   = (const float*)d_in[4];
  const float* sc_w  = (const float*)d_in[5];
  const float* sc_b  = (const float*)d_in[6];
  const float* c1w   = (const float*)d_in[7];
  const float* c1b   = (const float*)d_in[8];
  const float* f1w   = (const float*)d_in[9];
  const float* f1b   = (const float*)d_in[10];
  const float* k1w   = (const float*)d_in[11];
  const float* k1b   = (const float*)d_in[12];
  const float* c2w   = (const float*)d_in[13];
  const float* c2b   = (const float*)d_in[14];
  const float* f2w   = (const float*)d_in[15];
  const float* f2b   = (const float*)d_in[16];
  const float* k2w   = (const float*)d_in[17];
  const float* k2b   = (const float*)d_in[18];
  const float* gamma = (const float*)d_in[19];
  const float* beta  = (const float*)d_in[20];
  const float* clsw  = (const float*)d_in[21];
  const float* clsb  = (const float*)d_in[22];
  float* out = (float*)d_out;
  float* ws = (float*)d_ws;

  float* pre   = ws + OFF_PRE;
  float* hl    = ws + OFF_HL;
  float* hseq  = ws + OFF_HSEQ;
  float* xin1  = ws + OFF_XIN1;
  float* cbuf  = ws + OFF_C;
  float* s4    = ws + OFF_S4;
  float* xin2  = ws + OFF_XIN2;
  float* out2  = ws + OFF_OUT2;
  float* out3  = ws + OFF_OUT3;
  float* fused = ws + OFF_FUSED;
  double* stats = (double*)(ws + OFF_STATS);

  k_pregate<<<TT, 64, 0, stream>>>(x, wih, bih, bhh, pre);
  k_lstm<<<1, 64, 0, stream>>>(pre, whh, hseq);
  k_sconv<<<(TT * 20 + 255) / 256, 256, 0, stream>>>(hseq, sc_w, sc_b, xin1);
  // hr module 1
  k_lif3<<<1, 64, 0, stream>>>(xin1, hl);
  k_conv60<<<(TT * 20 + 255) / 256, 256, 0, stream>>>(hl, c1w, c1b, cbuf);
  k_lifseq<<<1, 64, 0, stream>>>(cbuf, s4);
  k_fcskip<20><<<(TT * 20 + 255) / 256, 256, 0, stream>>>(s4, xin1, f1w, f1b, k1w, k1b, xin2);
  // hr module 2
  k_lif3<<<1, 64, 0, stream>>>(xin2, hl);
  k_conv60<<<(TT * 20 + 255) / 256, 256, 0, stream>>>(hl, c2w, c2b, cbuf);
  k_lifseq<<<1, 64, 0, stream>>>(cbuf, s4);
  k_fcskip<10><<<(TT * 10 + 255) / 256, 256, 0, stream>>>(s4, xin2, f2w, f2b, k2w, k2b, out2);
  // final LIF over batch axis + head
  k_flif<<<1, 1024, 0, stream>>>(out2, out3);
  k_fused<<<512, 256, 0, stream>>>(out3, fused, stats);
  k_head<<<1, 1024, 0, stream>>>(fused, stats, gamma, beta, clsw, clsb, out);
}

// Round 3
// 1077.794 us; speedup vs baseline: 19.4567x; 15.7883x over previous
//
#include <hip/hip_runtime.h>
#include <math.h>

// ---------------------------------------------------------------------------
// HRSNN. R3: chunk-parallel scans. All recurrences here are strongly
// contracting (LIF: a=1-1/tau <= 0.31/step; LSTM: forget gate ~0.5/step), so
// each chunk restarts from state 0 with a warm-up region long enough that the
// boundary-state influence underflows to exactly zero in fp32 -> outputs are
// bit-identical to the sequential R2 kernel (formulas & rounding order kept
// untouched). This turns 5 serial 51200-step scans into ~100-way parallel.
// ---------------------------------------------------------------------------

namespace {
constexpr int TT = 51200;  // B*T
constexpr double TAU1d = 1.2231301601484298;  // exp(-1.5)+1
constexpr double TAU2d = 1.3678794411714423;  // exp(-1.0)+1  (== TAU4)
constexpr double TAU3d = 1.4493289641172216;  // exp(-0.8)+1

constexpr int LSTM_L = 512, LSTM_W = 256, LSTM_NCH = TT / LSTM_L;  // 100
constexpr int LIF_L  = 512, LIF_W  = 128, LIF_NCH  = TT / LIF_L;   // 100
constexpr int FB_L   = 64,  FB_W   = 64,  FB_NCH   = 512 / FB_L;   // 8

// workspace layout (float offsets). HL overlays PRE+HSEQ (dead by then).
constexpr size_t OFF_PRE   = 0;         // 51200*40 (+320 over-read pad)
constexpr size_t OFF_HL    = 0;         // 51200*60
constexpr size_t OFF_HSEQ  = 2048320;   // 51200*10
constexpr size_t OFF_XIN1  = 3072000;   // 51200*20 (+over-read into C: ok)
constexpr size_t OFF_C     = 4096000;   // 51200*20
constexpr size_t OFF_S4    = 5120000;   // 51200*20
constexpr size_t OFF_XIN2  = 6144000;   // 51200*20
constexpr size_t OFF_OUT2  = 7168000;   // 51200*10
constexpr size_t OFF_OUT3  = 7680000;   // 512*100*10
constexpr size_t OFF_FUSED = 8192000;   // 512*200
constexpr size_t OFF_STATS = 8294400;   // 512*2 doubles
}  // namespace

__device__ __forceinline__ float rcp_nr(float d) {
  float r = __builtin_amdgcn_rcpf(d);
  return r * (2.0f - d * r);  // one Newton step: ~1ulp
}

// K1: pregate[t][l] = sum_c x[b][c][tt]*wih[l][c] + bih[l] + bhh[l]
__global__ void __launch_bounds__(64) k_pregate(const float* __restrict__ x,
                                                const float* __restrict__ wih,
                                                const float* __restrict__ bih,
                                                const float* __restrict__ bhh,
                                                float* __restrict__ pre) {
  __shared__ float xs[64];
  const int t = blockIdx.x;
  const int b = t / 100;
  const int tt = t - b * 100;
  const int lane = threadIdx.x;
  xs[lane] = x[b * 6400 + lane * 100 + tt];
  __syncthreads();
  if (lane < 40) {
    float acc = bih[lane] + bhh[lane];
    const float* w = wih + lane * 64;
#pragma unroll
    for (int c = 0; c < 64; ++c) acc = fmaf(xs[c], w[c], acc);
    pre[t * 40 + lane] = acc;
  }
}

// K2: chunk-parallel LSTM. One wave per chunk; lane l<40 owns gate l
// (i:0-9 f:10-19 g:20-29 o:30-39); per-lane activation; bpermute gather of
// activated gates; h broadcast via readlane. Warm-up LSTM_W steps from
// (h,c)=(0,0): forget-gate contraction underflows boundary state to exact 0
// before the output region -> bit-exact vs the R2 sequential scan.
__global__ void __launch_bounds__(64) k_lstm(const float* __restrict__ pre,
                                             const float* __restrict__ whh,
                                             float* __restrict__ hseq) {
  const int lane = threadIdx.x;
  const int l = lane < 40 ? lane : 0;
  float wh[10];
#pragma unroll
  for (int j = 0; j < 10; ++j) wh[j] = whh[l * 10 + j];
  const int jm = lane % 10;
  const bool is_g = (l >= 20) & (l < 30);
  const float sel = is_g ? 2.0f : -1.0f;
  const int outstart = blockIdx.x * LSTM_L;
  const int start = (outstart >= LSTM_W) ? outstart - LSTM_W : 0;  // mult of 8
  const int end = outstart + LSTM_L;
  float cst = 0.0f;
  float h[10];
#pragma unroll
  for (int j = 0; j < 10; ++j) h[j] = 0.0f;
  float pbuf[8];
#pragma unroll
  for (int i = 0; i < 8; ++i) pbuf[i] = pre[(start + i) * 40 + l];
#pragma unroll 8
  for (int t = start; t < end; ++t) {
    float g = pbuf[t & 7];
    pbuf[t & 7] = pre[(t + 8) * 40 + l];  // last chunk over-reads into pad
#pragma unroll
    for (int j = 0; j < 10; ++j) g = fmaf(h[j], wh[j], g);  // order as R2
    const float e = __expf(sel * g);
    const float r = rcp_nr(1.0f + e);
    const float act = is_g ? (1.0f - 2.0f * r) : r;
    const float ai = __shfl(act, jm);
    const float af = __shfl(act, jm + 10);
    const float ag = __shfl(act, jm + 20);
    const float ao = __shfl(act, jm + 30);
    cst = af * cst + ai * ag;
    const float hn = ao * (1.0f - 2.0f * rcp_nr(__expf(2.0f * cst) + 1.0f));
    if ((lane < 10) & (t >= outstart)) hseq[t * 10 + lane] = hn;
#pragma unroll
    for (int j = 0; j < 10; ++j)
      h[j] = __uint_as_float(__builtin_amdgcn_readlane(__float_as_uint(hn), j));
  }
}

// K3: conv_out = hseq @ sc_w[:,0,:].T + sc_b   (pointwise in t)
__global__ void __launch_bounds__(256) k_sconv(const float* __restrict__ hseq,
                                               const float* __restrict__ sw,
                                               const float* __restrict__ sb,
                                               float* __restrict__ xin) {
  const int i = blockIdx.x * 256 + threadIdx.x;
  if (i >= TT * 20) return;
  const int t = i / 20;
  const int o = i - t * 20;
  const float* hp = hseq + t * 10;
  const float* wp = sw + o * 10;
  float acc = sb[o];
#pragma unroll
  for (int j = 0; j < 10; ++j) acc = fmaf(hp[j], wp[j], acc);
  xin[i] = acc;
}

// K4/K8: 60 LIF chains x LIF_NCH chunks. Warm-up LIF_W steps from v=0:
// a<=0.31 => boundary influence underflows to exact 0 within ~60 steps.
__global__ void __launch_bounds__(64) k_lif3(const float* __restrict__ xin,
                                             float* __restrict__ hl) {
  const int lane = threadIdx.x;
  const int cid = lane < 60 ? lane : 0;
  const int f = cid / 3;
  const int k = cid - f * 3;
  const float tau = (k == 0) ? (float)TAU1d : (k == 1) ? (float)TAU2d : (float)TAU3d;
  const float rt = 1.0f / tau;
  const float th = (k == 0) ? 0.14f : (k == 1) ? 0.08f : 0.06f;
  const int outstart = blockIdx.x * LIF_L;
  const int start = (outstart >= LIF_W) ? outstart - LIF_W : 0;  // mult of 16
  const int end = outstart + LIF_L;
  float v = 0.0f;
  float xb[16];
#pragma unroll
  for (int i = 0; i < 16; ++i) xb[i] = xin[(start + i) * 20 + f];
#pragma unroll 16
  for (int t = start; t < end; ++t) {
    const float x = xb[t & 15];
    xb[t & 15] = xin[(t + 16) * 20 + f];  // last chunk over-reads (dead pad)
    v = fmaf(x - v, rt, v);
    const float sp = (v - th >= 0.0f) ? 1.0f : 0.0f;
    if ((lane < 60) & (t >= outstart)) hl[t * 60 + lane] = sp;
    v = (sp != 0.0f) ? 0.0f : v;
  }
}

// K5/K9: c[t][o] = sum_{f,k} hl[t][f][k]*conv_w[o][f][k] + conv_b[o]
__global__ void __launch_bounds__(256) k_conv60(const float* __restrict__ hl,
                                                const float* __restrict__ cw,
                                                const float* __restrict__ cb,
                                                float* __restrict__ cout) {
  const int i = blockIdx.x * 256 + threadIdx.x;
  if (i >= TT * 20) return;
  const int t = i / 20;
  const int o = i - t * 20;
  const float* hp = hl + t * 60;
  const float* wp = cw + o * 60;
  float acc = cb[o];
#pragma unroll
  for (int d = 0; d < 60; ++d) acc = fmaf(hp[d], wp[d], acc);
  cout[i] = acc;
}

// K6/K10: 20 LIF chains (tau4, theta=0.08) x LIF_NCH chunks.
__global__ void __launch_bounds__(64) k_lifseq(const float* __restrict__ xin,
                                               float* __restrict__ sp_out) {
  const int lane = threadIdx.x;
  const int f = lane < 20 ? lane : 0;
  const float rt = 1.0f / (float)TAU2d;
  const int outstart = blockIdx.x * LIF_L;
  const int start = (outstart >= LIF_W) ? outstart - LIF_W : 0;
  const int end = outstart + LIF_L;
  float v = 0.0f;
  float xb[16];
#pragma unroll
  for (int i = 0; i < 16; ++i) xb[i] = xin[(start + i) * 20 + f];
#pragma unroll 16
  for (int t = start; t < end; ++t) {
    const float x = xb[t & 15];
    xb[t & 15] = xin[(t + 16) * 20 + f];
    v = fmaf(x - v, rt, v);
    const float sp = (v - 0.08f >= 0.0f) ? 1.0f : 0.0f;
    if ((lane < 20) & (t >= outstart)) sp_out[t * 20 + lane] = sp;
    v = (sp != 0.0f) ? 0.0f : v;
  }
}

// K7/K11: out = s4@fc_w.T + fc_b + xin@skip_w[:,:,0].T + skip_b
template <int O>
__global__ void __launch_bounds__(256) k_fcskip(const float* __restrict__ s4,
                                                const float* __restrict__ xin,
                                                const float* __restrict__ fw,
                                                const float* __restrict__ fb,
                                                const float* __restrict__ sw,
                                                const float* __restrict__ sb,
                                                float* __restrict__ outp) {
  const int i = blockIdx.x * 256 + threadIdx.x;
  if (i >= TT * O) return;
  const int t = i / O;
  const int o = i - t * O;
  const float* s = s4 + t * 20;
  const float* xi = xin + t * 20;
  const float* fwp = fw + o * 20;
  const float* swp = sw + o * 20;
  float acc = fb[o] + sb[o];
#pragma unroll
  for (int j = 0; j < 20; ++j) acc = fmaf(s[j], fwp[j], fmaf(xi[j], swp[j], acc));
  outp[i] = acc;
}

// K12: final LIF over batch axis: 1000 chains, chunked over b (L=W=64).
__global__ void __launch_bounds__(256) k_flif(const float* __restrict__ out2,
                                              float* __restrict__ out3) {
  const int idx = blockIdx.x * 256 + threadIdx.x;
  if (idx >= FB_NCH * 1000) return;
  const int chunk = idx / 1000;
  const int chain = idx - chunk * 1000;
  const float rt = 1.0f / (float)TAU2d;
  const int outstart = chunk * FB_L;
  const int start = (outstart >= FB_W) ? outstart - FB_W : 0;  // mult of 4
  const int end = outstart + FB_L;
  float v = 0.0f;
  float xb[4];
#pragma unroll
  for (int i = 0; i < 4; ++i) xb[i] = out2[(start + i) * 1000 + chain];
#pragma unroll 4
  for (int b = start; b < end; ++b) {
    const float x = xb[b & 3];
    xb[b & 3] = out2[(b + 4) * 1000 + chain];  // over-read harmless (unused)
    v = fmaf(x - v, rt, v);
    const float sp = (v - 0.08f >= 0.0f) ? 1.0f : 0.0f;
    if (b >= outstart) out3[b * 1000 + chain] = sp;
    v = (sp != 0.0f) ? 0.0f : v;
  }
}

// K13: dp -> avg -> fused; per-block (per-b) partial sum/sumsq in double.
__global__ void __launch_bounds__(256) k_fused(const float* __restrict__ out3,
                                               float* __restrict__ fused,
                                               double* __restrict__ stats) {
  __shared__ float dp_s[200];
  __shared__ float avg_s[20];
  __shared__ double red_s[8];
  const int b = blockIdx.x;
  const int tid = threadIdx.x;
  if (tid < 200) {
    const int f = tid / 20;
    const int seg = tid - f * 20;
    const float* base = out3 + b * 1000 + seg * 50 + f;
    dp_s[tid] = ((base[30] + base[40]) - (base[0] + base[10])) * 0.5f;
  }
  __syncthreads();
  if (tid < 20) {
    float s = 0.0f;
#pragma unroll
    for (int f = 0; f < 10; ++f) s += dp_s[f * 20 + tid];
    avg_s[tid] = s / 10.0f;
  }
  __syncthreads();
  float val = 0.0f;
  if (tid < 200) {
    val = dp_s[tid] * avg_s[tid % 20];
    fused[b * 200 + tid] = val;
  }
  double sv = (double)val, sq = (double)val * (double)val;
#pragma unroll
  for (int off = 32; off > 0; off >>= 1) {
    sv += __shfl_down(sv, off);
    sq += __shfl_down(sq, off);
  }
  const int wid = tid >> 6;
  if ((tid & 63) == 0) { red_s[wid * 2] = sv; red_s[wid * 2 + 1] = sq; }
  __syncthreads();
  if (tid == 0) {
    double S = 0.0, Q = 0.0;
#pragma unroll
    for (int w = 0; w < 4; ++w) { S += red_s[w * 2]; Q += red_s[w * 2 + 1]; }
    stats[b * 2] = S;
    stats[b * 2 + 1] = Q;
  }
}

// K14: reduce stats -> mean/var -> bn -> logits -> log_softmax. One block.
__global__ void __launch_bounds__(1024) k_head(const float* __restrict__ fused,
                                               const double* __restrict__ stats,
                                               const float* __restrict__ gamma,
                                               const float* __restrict__ beta,
                                               const float* __restrict__ clsw,
                                               const float* __restrict__ clsb,
                                               float* __restrict__ out) {
  __shared__ double redS[16], redQ[16];
  __shared__ float cls_s[600];
  __shared__ float cb_s[3];
  __shared__ float mr_s[2];
  const int tid = threadIdx.x;
  if (tid < 600) cls_s[tid] = clsw[tid];
  if (tid < 3) cb_s[tid] = clsb[tid];
  double s = 0.0, q = 0.0;
  if (tid < 512) { s = stats[2 * tid]; q = stats[2 * tid + 1]; }
#pragma unroll
  for (int off = 32; off > 0; off >>= 1) {
    s += __shfl_down(s, off);
    q += __shfl_down(q, off);
  }
  const int wid = tid >> 6;
  if ((tid & 63) == 0) { redS[wid] = s; redQ[wid] = q; }
  __syncthreads();
  if (tid == 0) {
    double S = 0.0, Q = 0.0;
#pragma unroll
    for (int w = 0; w < 16; ++w) { S += redS[w]; Q += redQ[w]; }
    const double mean = S / 102400.0;
    const double var = Q / 102400.0 - mean * mean;
    mr_s[0] = (float)mean;
    mr_s[1] = (float)(1.0 / sqrt(var + 1e-5));
  }
  __syncthreads();
  if (tid < 512) {
    const float mean = mr_s[0], rsig = mr_s[1];
    const float ga = gamma[0], be = beta[0];
    const float* fr = fused + tid * 200;
    float l0 = cb_s[0], l1 = cb_s[1], l2 = cb_s[2];
    for (int j = 0; j < 200; ++j) {
      const float bn = (fr[j] - mean) * rsig * ga + be;
      l0 = fmaf(bn, cls_s[j], l0);
      l1 = fmaf(bn, cls_s[200 + j], l1);
      l2 = fmaf(bn, cls_s[400 + j], l2);
    }
    const float m = fmaxf(l0, fmaxf(l1, l2));
    const float lse = m + logf(expf(l0 - m) + expf(l1 - m) + expf(l2 - m));
    out[tid * 3 + 0] = l0 - lse;
    out[tid * 3 + 1] = l1 - lse;
    out[tid * 3 + 2] = l2 - lse;
  }
}

extern "C" void kernel_launch(void* const* d_in, const int* in_sizes, int n_in,
                              void* d_out, int out_size, void* d_ws, size_t ws_size,
                              hipStream_t stream) {
  (void)in_sizes; (void)n_in; (void)out_size; (void)ws_size;
  const float* x     = (const float*)d_in[0];
  const float* wih   = (const float*)d_in[1];
  const float* whh   = (const float*)d_in[2];
  const float* bih   = (const float*)d_in[3];
  const float* bhh   = (const float*)d_in[4];
  const float* sc_w  = (const float*)d_in[5];
  const float* sc_b  = (const float*)d_in[6];
  const float* c1w   = (const float*)d_in[7];
  const float* c1b   = (const float*)d_in[8];
  const float* f1w   = (const float*)d_in[9];
  const float* f1b   = (const float*)d_in[10];
  const float* k1w   = (const float*)d_in[11];
  const float* k1b   = (const float*)d_in[12];
  const float* c2w   = (const float*)d_in[13];
  const float* c2b   = (const float*)d_in[14];
  const float* f2w   = (const float*)d_in[15];
  const float* f2b   = (const float*)d_in[16];
  const float* k2w   = (const float*)d_in[17];
  const float* k2b   = (const float*)d_in[18];
  const float* gamma = (const float*)d_in[19];
  const float* beta  = (const float*)d_in[20];
  const float* clsw  = (const float*)d_in[21];
  const float* clsb  = (const float*)d_in[22];
  float* out = (float*)d_out;
  float* ws = (float*)d_ws;

  float* pre   = ws + OFF_PRE;
  float* hl    = ws + OFF_HL;
  float* hseq  = ws + OFF_HSEQ;
  float* xin1  = ws + OFF_XIN1;
  float* cbuf  = ws + OFF_C;
  float* s4    = ws + OFF_S4;
  float* xin2  = ws + OFF_XIN2;
  float* out2  = ws + OFF_OUT2;
  float* out3  = ws + OFF_OUT3;
  float* fused = ws + OFF_FUSED;
  double* stats = (double*)(ws + OFF_STATS);

  k_pregate<<<TT, 64, 0, stream>>>(x, wih, bih, bhh, pre);
  k_lstm<<<LSTM_NCH, 64, 0, stream>>>(pre, whh, hseq);
  k_sconv<<<(TT * 20 + 255) / 256, 256, 0, stream>>>(hseq, sc_w, sc_b, xin1);
  // hr module 1
  k_lif3<<<LIF_NCH, 64, 0, stream>>>(xin1, hl);
  k_conv60<<<(TT * 20 + 255) / 256, 256, 0, stream>>>(hl, c1w, c1b, cbuf);
  k_lifseq<<<LIF_NCH, 64, 0, stream>>>(cbuf, s4);
  k_fcskip<20><<<(TT * 20 + 255) / 256, 256, 0, stream>>>(s4, xin1, f1w, f1b, k1w, k1b, xin2);
  // hr module 2
  k_lif3<<<LIF_NCH, 64, 0, stream>>>(xin2, hl);
  k_conv60<<<(TT * 20 + 255) / 256, 256, 0, stream>>>(hl, c2w, c2b, cbuf);
  k_lifseq<<<LIF_NCH, 64, 0, stream>>>(cbuf, s4);
  k_fcskip<10><<<(TT * 10 + 255) / 256, 256, 0, stream>>>(s4, xin2, f2w, f2b, k2w, k2b, out2);
  // final LIF over batch axis + head
  k_flif<<<(FB_NCH * 1000 + 255) / 256, 256, 0, stream>>>(out2, out3);
  k_fused<<<512, 256, 0, stream>>>(out3, fused, stats);
  k_head<<<1, 1024, 0, stream>>>(fused, stats, gamma, beta, clsw, clsb, out);
}

// Round 4
// 467.288 us; speedup vs baseline: 44.8766x; 2.3065x over previous
//
#include <hip/hip_runtime.h>
#include <math.h>

// ---------------------------------------------------------------------------
// HRSNN. R4: shorter chunks. Contraction-in-fp32 means chunk trajectories
// merge BIT-EXACTLY with the sequential scan once the boundary difference
// drops below 1/2 ulp: LSTM ~0.6/step => W=128 (2^-98); LIF a<=0.31 => W=64
// (2^-108); batch-LIF a=0.27 => W=32. R3 (W=256/128) confirmed bit-identical
// outputs (absmax pinned at 0.125). Steps/chunk: LSTM 768->192, LIF 640->128.
// ---------------------------------------------------------------------------

namespace {
constexpr int TT = 51200;  // B*T
constexpr double TAU1d = 1.2231301601484298;  // exp(-1.5)+1
constexpr double TAU2d = 1.3678794411714423;  // exp(-1.0)+1  (== TAU4)
constexpr double TAU3d = 1.4493289641172216;  // exp(-0.8)+1

constexpr int LSTM_L = 64, LSTM_W = 128, LSTM_NCH = TT / LSTM_L;  // 800
constexpr int LIF_L  = 64, LIF_W  = 64,  LIF_NCH  = TT / LIF_L;   // 800
constexpr int FB_L   = 32, FB_W   = 32,  FB_NCH   = 512 / FB_L;   // 16

// workspace layout (float offsets). HL overlays PRE+HSEQ (dead by then).
constexpr size_t OFF_PRE   = 0;         // 51200*40 (+320 over-read pad)
constexpr size_t OFF_HL    = 0;         // 51200*60
constexpr size_t OFF_HSEQ  = 2048320;   // 51200*10
constexpr size_t OFF_XIN1  = 3072000;   // 51200*20 (+over-read into C: ok)
constexpr size_t OFF_C     = 4096000;   // 51200*20
constexpr size_t OFF_S4    = 5120000;   // 51200*20
constexpr size_t OFF_XIN2  = 6144000;   // 51200*20
constexpr size_t OFF_OUT2  = 7168000;   // 51200*10
constexpr size_t OFF_OUT3  = 7680000;   // 512*100*10
constexpr size_t OFF_FUSED = 8192000;   // 512*200
constexpr size_t OFF_STATS = 8294400;   // 512*2 doubles
}  // namespace

__device__ __forceinline__ float rcp_nr(float d) {
  float r = __builtin_amdgcn_rcpf(d);
  return r * (2.0f - d * r);  // one Newton step: ~1ulp
}

// K1: pregate[t][l] = sum_c x[b][c][tt]*wih[l][c] + bih[l] + bhh[l]
__global__ void __launch_bounds__(64) k_pregate(const float* __restrict__ x,
                                                const float* __restrict__ wih,
                                                const float* __restrict__ bih,
                                                const float* __restrict__ bhh,
                                                float* __restrict__ pre) {
  __shared__ float xs[64];
  const int t = blockIdx.x;
  const int b = t / 100;
  const int tt = t - b * 100;
  const int lane = threadIdx.x;
  xs[lane] = x[b * 6400 + lane * 100 + tt];
  __syncthreads();
  if (lane < 40) {
    float acc = bih[lane] + bhh[lane];
    const float* w = wih + lane * 64;
#pragma unroll
    for (int c = 0; c < 64; ++c) acc = fmaf(xs[c], w[c], acc);
    pre[t * 40 + lane] = acc;
  }
}

// K2: chunk-parallel LSTM. One wave per chunk; lane l<40 owns gate l
// (i:0-9 f:10-19 g:20-29 o:30-39); per-lane activation; bpermute gather of
// activated gates; h broadcast via readlane. Warm-up LSTM_W steps from
// (h,c)=(0,0) merges bit-exactly with the sequential trajectory.
__global__ void __launch_bounds__(64) k_lstm(const float* __restrict__ pre,
                                             const float* __restrict__ whh,
                                             float* __restrict__ hseq) {
  const int lane = threadIdx.x;
  const int l = lane < 40 ? lane : 0;
  float wh[10];
#pragma unroll
  for (int j = 0; j < 10; ++j) wh[j] = whh[l * 10 + j];
  const int jm = lane % 10;
  const bool is_g = (l >= 20) & (l < 30);
  const float sel = is_g ? 2.0f : -1.0f;
  const int outstart = blockIdx.x * LSTM_L;
  const int start = (outstart >= LSTM_W) ? outstart - LSTM_W : 0;  // mult of 8
  const int end = outstart + LSTM_L;
  float cst = 0.0f;
  float h[10];
#pragma unroll
  for (int j = 0; j < 10; ++j) h[j] = 0.0f;
  float pbuf[8];
#pragma unroll
  for (int i = 0; i < 8; ++i) pbuf[i] = pre[(start + i) * 40 + l];
#pragma unroll 8
  for (int t = start; t < end; ++t) {
    float g = pbuf[t & 7];
    pbuf[t & 7] = pre[(t + 8) * 40 + l];  // last chunk over-reads into pad
#pragma unroll
    for (int j = 0; j < 10; ++j) g = fmaf(h[j], wh[j], g);  // order as R2
    const float e = __expf(sel * g);
    const float r = rcp_nr(1.0f + e);
    const float act = is_g ? (1.0f - 2.0f * r) : r;
    const float ai = __shfl(act, jm);
    const float af = __shfl(act, jm + 10);
    const float ag = __shfl(act, jm + 20);
    const float ao = __shfl(act, jm + 30);
    cst = af * cst + ai * ag;
    const float hn = ao * (1.0f - 2.0f * rcp_nr(__expf(2.0f * cst) + 1.0f));
    if ((lane < 10) & (t >= outstart)) hseq[t * 10 + lane] = hn;
#pragma unroll
    for (int j = 0; j < 10; ++j)
      h[j] = __uint_as_float(__builtin_amdgcn_readlane(__float_as_uint(hn), j));
  }
}

// K3: conv_out = hseq @ sc_w[:,0,:].T + sc_b   (pointwise in t)
__global__ void __launch_bounds__(256) k_sconv(const float* __restrict__ hseq,
                                               const float* __restrict__ sw,
                                               const float* __restrict__ sb,
                                               float* __restrict__ xin) {
  const int i = blockIdx.x * 256 + threadIdx.x;
  if (i >= TT * 20) return;
  const int t = i / 20;
  const int o = i - t * 20;
  const float* hp = hseq + t * 10;
  const float* wp = sw + o * 10;
  float acc = sb[o];
#pragma unroll
  for (int j = 0; j < 10; ++j) acc = fmaf(hp[j], wp[j], acc);
  xin[i] = acc;
}

// K4/K8: 60 LIF chains x LIF_NCH chunks. Warm-up LIF_W=64 from v=0:
// a<=0.31 -> boundary influence below 1/2 ulp in <=50 steps -> exact merge.
__global__ void __launch_bounds__(64) k_lif3(const float* __restrict__ xin,
                                             float* __restrict__ hl) {
  const int lane = threadIdx.x;
  const int cid = lane < 60 ? lane : 0;
  const int f = cid / 3;
  const int k = cid - f * 3;
  const float tau = (k == 0) ? (float)TAU1d : (k == 1) ? (float)TAU2d : (float)TAU3d;
  const float rt = 1.0f / tau;
  const float th = (k == 0) ? 0.14f : (k == 1) ? 0.08f : 0.06f;
  const int outstart = blockIdx.x * LIF_L;
  const int start = (outstart >= LIF_W) ? outstart - LIF_W : 0;  // mult of 16
  const int end = outstart + LIF_L;
  float v = 0.0f;
  float xb[16];
#pragma unroll
  for (int i = 0; i < 16; ++i) xb[i] = xin[(start + i) * 20 + f];
#pragma unroll 16
  for (int t = start; t < end; ++t) {
    const float x = xb[t & 15];
    xb[t & 15] = xin[(t + 16) * 20 + f];  // last chunk over-reads (dead pad)
    v = fmaf(x - v, rt, v);
    const float sp = (v - th >= 0.0f) ? 1.0f : 0.0f;
    if ((lane < 60) & (t >= outstart)) hl[t * 60 + lane] = sp;
    v = (sp != 0.0f) ? 0.0f : v;
  }
}

// K5/K9: c[t][o] = sum_{f,k} hl[t][f][k]*conv_w[o][f][k] + conv_b[o]
__global__ void __launch_bounds__(256) k_conv60(const float* __restrict__ hl,
                                                const float* __restrict__ cw,
                                                const float* __restrict__ cb,
                                                float* __restrict__ cout) {
  const int i = blockIdx.x * 256 + threadIdx.x;
  if (i >= TT * 20) return;
  const int t = i / 20;
  const int o = i - t * 20;
  const float* hp = hl + t * 60;
  const float* wp = cw + o * 60;
  float acc = cb[o];
#pragma unroll
  for (int d = 0; d < 60; ++d) acc = fmaf(hp[d], wp[d], acc);
  cout[i] = acc;
}

// K6/K10: 20 LIF chains (tau4, theta=0.08) x LIF_NCH chunks.
__global__ void __launch_bounds__(64) k_lifseq(const float* __restrict__ xin,
                                               float* __restrict__ sp_out) {
  const int lane = threadIdx.x;
  const int f = lane < 20 ? lane : 0;
  const float rt = 1.0f / (float)TAU2d;
  const int outstart = blockIdx.x * LIF_L;
  const int start = (outstart >= LIF_W) ? outstart - LIF_W : 0;
  const int end = outstart + LIF_L;
  float v = 0.0f;
  float xb[16];
#pragma unroll
  for (int i = 0; i < 16; ++i) xb[i] = xin[(start + i) * 20 + f];
#pragma unroll 16
  for (int t = start; t < end; ++t) {
    const float x = xb[t & 15];
    xb[t & 15] = xin[(t + 16) * 20 + f];
    v = fmaf(x - v, rt, v);
    const float sp = (v - 0.08f >= 0.0f) ? 1.0f : 0.0f;
    if ((lane < 20) & (t >= outstart)) sp_out[t * 20 + lane] = sp;
    v = (sp != 0.0f) ? 0.0f : v;
  }
}

// K7/K11: out = s4@fc_w.T + fc_b + xin@skip_w[:,:,0].T + skip_b
template <int O>
__global__ void __launch_bounds__(256) k_fcskip(const float* __restrict__ s4,
                                                const float* __restrict__ xin,
                                                const float* __restrict__ fw,
                                                const float* __restrict__ fb,
                                                const float* __restrict__ sw,
                                                const float* __restrict__ sb,
                                                float* __restrict__ outp) {
  const int i = blockIdx.x * 256 + threadIdx.x;
  if (i >= TT * O) return;
  const int t = i / O;
  const int o = i - t * O;
  const float* s = s4 + t * 20;
  const float* xi = xin + t * 20;
  const float* fwp = fw + o * 20;
  const float* swp = sw + o * 20;
  float acc = fb[o] + sb[o];
#pragma unroll
  for (int j = 0; j < 20; ++j) acc = fmaf(s[j], fwp[j], fmaf(xi[j], swp[j], acc));
  outp[i] = acc;
}

// K12: final LIF over batch axis: 1000 chains, chunked over b (L=W=32).
__global__ void __launch_bounds__(256) k_flif(const float* __restrict__ out2,
                                              float* __restrict__ out3) {
  const int idx = blockIdx.x * 256 + threadIdx.x;
  if (idx >= FB_NCH * 1000) return;
  const int chunk = idx / 1000;
  const int chain = idx - chunk * 1000;
  const float rt = 1.0f / (float)TAU2d;
  const int outstart = chunk * FB_L;
  const int start = (outstart >= FB_W) ? outstart - FB_W : 0;  // mult of 4
  const int end = outstart + FB_L;
  float v = 0.0f;
  float xb[4];
#pragma unroll
  for (int i = 0; i < 4; ++i) xb[i] = out2[(start + i) * 1000 + chain];
#pragma unroll 4
  for (int b = start; b < end; ++b) {
    const float x = xb[b & 3];
    xb[b & 3] = out2[(b + 4) * 1000 + chain];  // over-read harmless (unused)
    v = fmaf(x - v, rt, v);
    const float sp = (v - 0.08f >= 0.0f) ? 1.0f : 0.0f;
    if (b >= outstart) out3[b * 1000 + chain] = sp;
    v = (sp != 0.0f) ? 0.0f : v;
  }
}

// K13: dp -> avg -> fused; per-block (per-b) partial sum/sumsq in double.
__global__ void __launch_bounds__(256) k_fused(const float* __restrict__ out3,
                                               float* __restrict__ fused,
                                               double* __restrict__ stats) {
  __shared__ float dp_s[200];
  __shared__ float avg_s[20];
  __shared__ double red_s[8];
  const int b = blockIdx.x;
  const int tid = threadIdx.x;
  if (tid < 200) {
    const int f = tid / 20;
    const int seg = tid - f * 20;
    const float* base = out3 + b * 1000 + seg * 50 + f;
    dp_s[tid] = ((base[30] + base[40]) - (base[0] + base[10])) * 0.5f;
  }
  __syncthreads();
  if (tid < 20) {
    float s = 0.0f;
#pragma unroll
    for (int f = 0; f < 10; ++f) s += dp_s[f * 20 + tid];
    avg_s[tid] = s / 10.0f;
  }
  __syncthreads();
  float val = 0.0f;
  if (tid < 200) {
    val = dp_s[tid] * avg_s[tid % 20];
    fused[b * 200 + tid] = val;
  }
  double sv = (double)val, sq = (double)val * (double)val;
#pragma unroll
  for (int off = 32; off > 0; off >>= 1) {
    sv += __shfl_down(sv, off);
    sq += __shfl_down(sq, off);
  }
  const int wid = tid >> 6;
  if ((tid & 63) == 0) { red_s[wid * 2] = sv; red_s[wid * 2 + 1] = sq; }
  __syncthreads();
  if (tid == 0) {
    double S = 0.0, Q = 0.0;
#pragma unroll
    for (int w = 0; w < 4; ++w) { S += red_s[w * 2]; Q += red_s[w * 2 + 1]; }
    stats[b * 2] = S;
    stats[b * 2 + 1] = Q;
  }
}

// K14: reduce stats -> mean/var -> bn -> logits -> log_softmax. One block.
__global__ void __launch_bounds__(1024) k_head(const float* __restrict__ fused,
                                               const double* __restrict__ stats,
                                               const float* __restrict__ gamma,
                                               const float* __restrict__ beta,
                                               const float* __restrict__ clsw,
                                               const float* __restrict__ clsb,
                                               float* __restrict__ out) {
  __shared__ double redS[16], redQ[16];
  __shared__ float cls_s[600];
  __shared__ float cb_s[3];
  __shared__ float mr_s[2];
  const int tid = threadIdx.x;
  if (tid < 600) cls_s[tid] = clsw[tid];
  if (tid < 3) cb_s[tid] = clsb[tid];
  double s = 0.0, q = 0.0;
  if (tid < 512) { s = stats[2 * tid]; q = stats[2 * tid + 1]; }
#pragma unroll
  for (int off = 32; off > 0; off >>= 1) {
    s += __shfl_down(s, off);
    q += __shfl_down(q, off);
  }
  const int wid = tid >> 6;
  if ((tid & 63) == 0) { redS[wid] = s; redQ[wid] = q; }
  __syncthreads();
  if (tid == 0) {
    double S = 0.0, Q = 0.0;
#pragma unroll
    for (int w = 0; w < 16; ++w) { S += redS[w]; Q += redQ[w]; }
    const double mean = S / 102400.0;
    const double var = Q / 102400.0 - mean * mean;
    mr_s[0] = (float)mean;
    mr_s[1] = (float)(1.0 / sqrt(var + 1e-5));
  }
  __syncthreads();
  if (tid < 512) {
    const float mean = mr_s[0], rsig = mr_s[1];
    const float ga = gamma[0], be = beta[0];
    const float* fr = fused + tid * 200;
    float l0 = cb_s[0], l1 = cb_s[1], l2 = cb_s[2];
    for (int j = 0; j < 200; ++j) {
      const float bn = (fr[j] - mean) * rsig * ga + be;
      l0 = fmaf(bn, cls_s[j], l0);
      l1 = fmaf(bn, cls_s[200 + j], l1);
      l2 = fmaf(bn, cls_s[400 + j], l2);
    }
    const float m = fmaxf(l0, fmaxf(l1, l2));
    const float lse = m + logf(expf(l0 - m) + expf(l1 - m) + expf(l2 - m));
    out[tid * 3 + 0] = l0 - lse;
    out[tid * 3 + 1] = l1 - lse;
    out[tid * 3 + 2] = l2 - lse;
  }
}

extern "C" void kernel_launch(void* const* d_in, const int* in_sizes, int n_in,
                              void* d_out, int out_size, void* d_ws, size_t ws_size,
                              hipStream_t stream) {
  (void)in_sizes; (void)n_in; (void)out_size; (void)ws_size;
  const float* x     = (const float*)d_in[0];
  const float* wih   = (const float*)d_in[1];
  const float* whh   = (const float*)d_in[2];
  const float* bih   = (const float*)d_in[3];
  const float* bhh   = (const float*)d_in[4];
  const float* sc_w  = (const float*)d_in[5];
  const float* sc_b  = (const float*)d_in[6];
  const float* c1w   = (const float*)d_in[7];
  const float* c1b   = (const float*)d_in[8];
  const float* f1w   = (const float*)d_in[9];
  const float* f1b   = (const float*)d_in[10];
  const float* k1w   = (const float*)d_in[11];
  const float* k1b   = (const float*)d_in[12];
  const float* c2w   = (const float*)d_in[13];
  const float* c2b   = (const float*)d_in[14];
  const float* f2w   = (const float*)d_in[15];
  const float* f2b   = (const float*)d_in[16];
  const float* k2w   = (const float*)d_in[17];
  const float* k2b   = (const float*)d_in[18];
  const float* gamma = (const float*)d_in[19];
  const float* beta  = (const float*)d_in[20];
  const float* clsw  = (const float*)d_in[21];
  const float* clsb  = (const float*)d_in[22];
  float* out = (float*)d_out;
  float* ws = (float*)d_ws;

  float* pre   = ws + OFF_PRE;
  float* hl    = ws + OFF_HL;
  float* hseq  = ws + OFF_HSEQ;
  float* xin1  = ws + OFF_XIN1;
  float* cbuf  = ws + OFF_C;
  float* s4    = ws + OFF_S4;
  float* xin2  = ws + OFF_XIN2;
  float* out2  = ws + OFF_OUT2;
  float* out3  = ws + OFF_OUT3;
  float* fused = ws + OFF_FUSED;
  double* stats = (double*)(ws + OFF_STATS);

  k_pregate<<<TT, 64, 0, stream>>>(x, wih, bih, bhh, pre);
  k_lstm<<<LSTM_NCH, 64, 0, stream>>>(pre, whh, hseq);
  k_sconv<<<(TT * 20 + 255) / 256, 256, 0, stream>>>(hseq, sc_w, sc_b, xin1);
  // hr module 1
  k_lif3<<<LIF_NCH, 64, 0, stream>>>(xin1, hl);
  k_conv60<<<(TT * 20 + 255) / 256, 256, 0, stream>>>(hl, c1w, c1b, cbuf);
  k_lifseq<<<LIF_NCH, 64, 0, stream>>>(cbuf, s4);
  k_fcskip<20><<<(TT * 20 + 255) / 256, 256, 0, stream>>>(s4, xin1, f1w, f1b, k1w, k1b, xin2);
  // hr module 2
  k_lif3<<<LIF_NCH, 64, 0, stream>>>(xin2, hl);
  k_conv60<<<(TT * 20 + 255) / 256, 256, 0, stream>>>(hl, c2w, c2b, cbuf);
  k_lifseq<<<LIF_NCH, 64, 0, stream>>>(cbuf, s4);
  k_fcskip<10><<<(TT * 10 + 255) / 256, 256, 0, stream>>>(s4, xin2, f2w, f2b, k2w, k2b, out2);
  // final LIF over batch axis + head
  k_flif<<<(FB_NCH * 1000 + 255) / 256, 256, 0, stream>>>(out2, out3);
  k_fused<<<512, 256, 0, stream>>>(out3, fused, stats);
  k_head<<<1, 1024, 0, stream>>>(fused, stats, gamma, beta, clsw, clsb, out);
}

// Round 5
// 336.381 us; speedup vs baseline: 62.3410x; 1.3892x over previous
//
#include <hip/hip_runtime.h>
#include <math.h>

// ---------------------------------------------------------------------------
// HRSNN. R5: (1) k_pregate rewritten as LDS-staged per-batch GEMM tile —
// the old version lane-strided x (stride 400B) causing 4x HBM over-fetch
// (52MB for a 13MB input, fetch-roofline-bound at 77us). (2) LIF chunks
// L=32/W=32 (contraction >=1.69 bits/step -> 2^-54 boundary residue,
// bit-exact merge confirmed empirically in R3/R4). (3) LSTM L=32 (W=128).
// All FP arithmetic order kept bit-identical to R4 (absmax must stay 0.125).
// ---------------------------------------------------------------------------

namespace {
constexpr int TT = 51200;  // B*T
constexpr double TAU1d = 1.2231301601484298;  // exp(-1.5)+1
constexpr double TAU2d = 1.3678794411714423;  // exp(-1.0)+1  (== TAU4)
constexpr double TAU3d = 1.4493289641172216;  // exp(-0.8)+1

constexpr int LSTM_L = 32, LSTM_W = 128, LSTM_NCH = TT / LSTM_L;  // 1600
constexpr int LIF_L  = 32, LIF_W  = 32,  LIF_NCH  = TT / LIF_L;   // 1600
constexpr int FB_L   = 32, FB_W   = 32,  FB_NCH   = 512 / FB_L;   // 16

// workspace layout (float offsets). HL overlays PRE+HSEQ (dead by then).
constexpr size_t OFF_PRE   = 0;         // 51200*40 (+320 over-read pad)
constexpr size_t OFF_HL    = 0;         // 51200*60
constexpr size_t OFF_HSEQ  = 2048320;   // 51200*10
constexpr size_t OFF_XIN1  = 3072000;   // 51200*20 (+over-read into C: ok)
constexpr size_t OFF_C     = 4096000;   // 51200*20
constexpr size_t OFF_S4    = 5120000;   // 51200*20
constexpr size_t OFF_XIN2  = 6144000;   // 51200*20
constexpr size_t OFF_OUT2  = 7168000;   // 51200*10
constexpr size_t OFF_OUT3  = 7680000;   // 512*100*10
constexpr size_t OFF_FUSED = 8192000;   // 512*200
constexpr size_t OFF_STATS = 8294400;   // 512*2 doubles
}  // namespace

__device__ __forceinline__ float rcp_nr(float d) {
  float r = __builtin_amdgcn_rcpf(d);
  return r * (2.0f - d * r);  // one Newton step: ~1ulp
}

// K1: pregate[(b*100+tt)*40+l] = sum_c x[b][c][tt]*wih[l][c] + bih[l]+bhh[l]
// One block per b. Stage x[b] (64x100) and wih^T (64x40) in LDS; each thread
// computes a 4(tt) x 4(l) register tile. Dot order (bias first, c ascending,
// single accumulator) is bit-identical to the previous version.
__global__ void __launch_bounds__(256) k_pregate(const float* __restrict__ x,
                                                 const float* __restrict__ wih,
                                                 const float* __restrict__ bih,
                                                 const float* __restrict__ bhh,
                                                 float* __restrict__ pre) {
  __shared__ __align__(16) float xs[6400];   // xs[c*100+tt]
  __shared__ __align__(16) float wT[2560];   // wT[c*40+l]
  __shared__ float bl[40];
  const int b = blockIdx.x;
  const int tid = threadIdx.x;
  for (int i = tid; i < 6400; i += 256) xs[i] = x[b * 6400 + i];  // coalesced
  for (int i = tid; i < 2560; i += 256) {
    const int c = i / 40;
    const int l = i - c * 40;
    wT[i] = wih[l * 64 + c];
  }
  if (tid < 40) bl[tid] = bih[tid] + bhh[tid];
  __syncthreads();
  if (tid >= 250) return;              // 25 tt-tiles x 10 l-tiles
  const int ttile = tid / 10;
  const int ltile = tid - ttile * 10;
  const int tt0 = ttile * 4;
  const int l0 = ltile * 4;
  float acc[4][4];
#pragma unroll
  for (int i = 0; i < 4; ++i)
#pragma unroll
    for (int j = 0; j < 4; ++j) acc[i][j] = bl[l0 + j];
#pragma unroll 8
  for (int c = 0; c < 64; ++c) {
    const float4 wv = *(const float4*)&wT[c * 40 + l0];
    const float4 xv = *(const float4*)&xs[c * 100 + tt0];
    const float xa[4] = {xv.x, xv.y, xv.z, xv.w};
    const float wa[4] = {wv.x, wv.y, wv.z, wv.w};
#pragma unroll
    for (int i = 0; i < 4; ++i)
#pragma unroll
      for (int j = 0; j < 4; ++j) acc[i][j] = fmaf(xa[i], wa[j], acc[i][j]);
  }
#pragma unroll
  for (int i = 0; i < 4; ++i) {
    float4 o;
    o.x = acc[i][0]; o.y = acc[i][1]; o.z = acc[i][2]; o.w = acc[i][3];
    *(float4*)&pre[(b * 100 + tt0 + i) * 40 + l0] = o;
  }
}

// K2: chunk-parallel LSTM. One wave per chunk; lane l<40 owns gate l
// (i:0-9 f:10-19 g:20-29 o:30-39); per-lane activation; bpermute gather of
// activated gates; h broadcast via readlane. Warm-up LSTM_W steps from
// (h,c)=(0,0) merges bit-exactly with the sequential trajectory.
__global__ void __launch_bounds__(64) k_lstm(const float* __restrict__ pre,
                                             const float* __restrict__ whh,
                                             float* __restrict__ hseq) {
  const int lane = threadIdx.x;
  const int l = lane < 40 ? lane : 0;
  float wh[10];
#pragma unroll
  for (int j = 0; j < 10; ++j) wh[j] = whh[l * 10 + j];
  const int jm = lane % 10;
  const bool is_g = (l >= 20) & (l < 30);
  const float sel = is_g ? 2.0f : -1.0f;
  const int outstart = blockIdx.x * LSTM_L;
  const int start = (outstart >= LSTM_W) ? outstart - LSTM_W : 0;  // mult of 32
  const int end = outstart + LSTM_L;
  float cst = 0.0f;
  float h[10];
#pragma unroll
  for (int j = 0; j < 10; ++j) h[j] = 0.0f;
  float pbuf[8];
#pragma unroll
  for (int i = 0; i < 8; ++i) pbuf[i] = pre[(start + i) * 40 + l];
#pragma unroll 8
  for (int t = start; t < end; ++t) {
    float g = pbuf[t & 7];
    pbuf[t & 7] = pre[(t + 8) * 40 + l];  // last chunk over-reads into pad
#pragma unroll
    for (int j = 0; j < 10; ++j) g = fmaf(h[j], wh[j], g);  // order as R2
    const float e = __expf(sel * g);
    const float r = rcp_nr(1.0f + e);
    const float act = is_g ? (1.0f - 2.0f * r) : r;
    const float ai = __shfl(act, jm);
    const float af = __shfl(act, jm + 10);
    const float ag = __shfl(act, jm + 20);
    const float ao = __shfl(act, jm + 30);
    cst = af * cst + ai * ag;
    const float hn = ao * (1.0f - 2.0f * rcp_nr(__expf(2.0f * cst) + 1.0f));
    if ((lane < 10) & (t >= outstart)) hseq[t * 10 + lane] = hn;
#pragma unroll
    for (int j = 0; j < 10; ++j)
      h[j] = __uint_as_float(__builtin_amdgcn_readlane(__float_as_uint(hn), j));
  }
}

// K3: conv_out = hseq @ sc_w[:,0,:].T + sc_b   (pointwise in t)
__global__ void __launch_bounds__(256) k_sconv(const float* __restrict__ hseq,
                                               const float* __restrict__ sw,
                                               const float* __restrict__ sb,
                                               float* __restrict__ xin) {
  const int i = blockIdx.x * 256 + threadIdx.x;
  if (i >= TT * 20) return;
  const int t = i / 20;
  const int o = i - t * 20;
  const float* hp = hseq + t * 10;
  const float* wp = sw + o * 10;
  float acc = sb[o];
#pragma unroll
  for (int j = 0; j < 10; ++j) acc = fmaf(hp[j], wp[j], acc);
  xin[i] = acc;
}

// K4/K8: 60 LIF chains x LIF_NCH chunks. Warm-up LIF_W=32 from v=0:
// a<=0.31 (>=1.69 bits/step) -> boundary residue 2^-54 -> exact merge.
__global__ void __launch_bounds__(64) k_lif3(const float* __restrict__ xin,
                                             float* __restrict__ hl) {
  const int lane = threadIdx.x;
  const int cid = lane < 60 ? lane : 0;
  const int f = cid / 3;
  const int k = cid - f * 3;
  const float tau = (k == 0) ? (float)TAU1d : (k == 1) ? (float)TAU2d : (float)TAU3d;
  const float rt = 1.0f / tau;
  const float th = (k == 0) ? 0.14f : (k == 1) ? 0.08f : 0.06f;
  const int outstart = blockIdx.x * LIF_L;
  const int start = (outstart >= LIF_W) ? outstart - LIF_W : 0;  // mult of 32
  const int end = outstart + LIF_L;
  float v = 0.0f;
  float xb[16];
#pragma unroll
  for (int i = 0; i < 16; ++i) xb[i] = xin[(start + i) * 20 + f];
#pragma unroll 16
  for (int t = start; t < end; ++t) {
    const float x = xb[t & 15];
    xb[t & 15] = xin[(t + 16) * 20 + f];  // last chunk over-reads (dead pad)
    v = fmaf(x - v, rt, v);
    const float sp = (v - th >= 0.0f) ? 1.0f : 0.0f;
    if ((lane < 60) & (t >= outstart)) hl[t * 60 + lane] = sp;
    v = (sp != 0.0f) ? 0.0f : v;
  }
}

// K5/K9: c[t][o] = sum_{f,k} hl[t][f][k]*conv_w[o][f][k] + conv_b[o]
__global__ void __launch_bounds__(256) k_conv60(const float* __restrict__ hl,
                                                const float* __restrict__ cw,
                                                const float* __restrict__ cb,
                                                float* __restrict__ cout) {
  const int i = blockIdx.x * 256 + threadIdx.x;
  if (i >= TT * 20) return;
  const int t = i / 20;
  const int o = i - t * 20;
  const float* hp = hl + t * 60;
  const float* wp = cw + o * 60;
  float acc = cb[o];
#pragma unroll
  for (int d = 0; d < 60; ++d) acc = fmaf(hp[d], wp[d], acc);
  cout[i] = acc;
}

// K6/K10: 20 LIF chains (tau4, theta=0.08) x LIF_NCH chunks.
__global__ void __launch_bounds__(64) k_lifseq(const float* __restrict__ xin,
                                               float* __restrict__ sp_out) {
  const int lane = threadIdx.x;
  const int f = lane < 20 ? lane : 0;
  const float rt = 1.0f / (float)TAU2d;
  const int outstart = blockIdx.x * LIF_L;
  const int start = (outstart >= LIF_W) ? outstart - LIF_W : 0;
  const int end = outstart + LIF_L;
  float v = 0.0f;
  float xb[16];
#pragma unroll
  for (int i = 0; i < 16; ++i) xb[i] = xin[(start + i) * 20 + f];
#pragma unroll 16
  for (int t = start; t < end; ++t) {
    const float x = xb[t & 15];
    xb[t & 15] = xin[(t + 16) * 20 + f];
    v = fmaf(x - v, rt, v);
    const float sp = (v - 0.08f >= 0.0f) ? 1.0f : 0.0f;
    if ((lane < 20) & (t >= outstart)) sp_out[t * 20 + lane] = sp;
    v = (sp != 0.0f) ? 0.0f : v;
  }
}

// K7/K11: out = s4@fc_w.T + fc_b + xin@skip_w[:,:,0].T + skip_b
template <int O>
__global__ void __launch_bounds__(256) k_fcskip(const float* __restrict__ s4,
                                                const float* __restrict__ xin,
                                                const float* __restrict__ fw,
                                                const float* __restrict__ fb,
                                                const float* __restrict__ sw,
                                                const float* __restrict__ sb,
                                                float* __restrict__ outp) {
  const int i = blockIdx.x * 256 + threadIdx.x;
  if (i >= TT * O) return;
  const int t = i / O;
  const int o = i - t * O;
  const float* s = s4 + t * 20;
  const float* xi = xin + t * 20;
  const float* fwp = fw + o * 20;
  const float* swp = sw + o * 20;
  float acc = fb[o] + sb[o];
#pragma unroll
  for (int j = 0; j < 20; ++j) acc = fmaf(s[j], fwp[j], fmaf(xi[j], swp[j], acc));
  outp[i] = acc;
}

// K12: final LIF over batch axis: 1000 chains, chunked over b (L=W=32).
__global__ void __launch_bounds__(256) k_flif(const float* __restrict__ out2,
                                              float* __restrict__ out3) {
  const int idx = blockIdx.x * 256 + threadIdx.x;
  if (idx >= FB_NCH * 1000) return;
  const int chunk = idx / 1000;
  const int chain = idx - chunk * 1000;
  const float rt = 1.0f / (float)TAU2d;
  const int outstart = chunk * FB_L;
  const int start = (outstart >= FB_W) ? outstart - FB_W : 0;  // mult of 4
  const int end = outstart + FB_L;
  float v = 0.0f;
  float xb[4];
#pragma unroll
  for (int i = 0; i < 4; ++i) xb[i] = out2[(start + i) * 1000 + chain];
#pragma unroll 4
  for (int b = start; b < end; ++b) {
    const float x = xb[b & 3];
    xb[b & 3] = out2[(b + 4) * 1000 + chain];  // over-read harmless (unused)
    v = fmaf(x - v, rt, v);
    const float sp = (v - 0.08f >= 0.0f) ? 1.0f : 0.0f;
    if (b >= outstart) out3[b * 1000 + chain] = sp;
    v = (sp != 0.0f) ? 0.0f : v;
  }
}

// K13: dp -> avg -> fused; per-block (per-b) partial sum/sumsq in double.
__global__ void __launch_bounds__(256) k_fused(const float* __restrict__ out3,
                                               float* __restrict__ fused,
                                               double* __restrict__ stats) {
  __shared__ float dp_s[200];
  __shared__ float avg_s[20];
  __shared__ double red_s[8];
  const int b = blockIdx.x;
  const int tid = threadIdx.x;
  if (tid < 200) {
    const int f = tid / 20;
    const int seg = tid - f * 20;
    const float* base = out3 + b * 1000 + seg * 50 + f;
    dp_s[tid] = ((base[30] + base[40]) - (base[0] + base[10])) * 0.5f;
  }
  __syncthreads();
  if (tid < 20) {
    float s = 0.0f;
#pragma unroll
    for (int f = 0; f < 10; ++f) s += dp_s[f * 20 + tid];
    avg_s[tid] = s / 10.0f;
  }
  __syncthreads();
  float val = 0.0f;
  if (tid < 200) {
    val = dp_s[tid] * avg_s[tid % 20];
    fused[b * 200 + tid] = val;
  }
  double sv = (double)val, sq = (double)val * (double)val;
#pragma unroll
  for (int off = 32; off > 0; off >>= 1) {
    sv += __shfl_down(sv, off);
    sq += __shfl_down(sq, off);
  }
  const int wid = tid >> 6;
  if ((tid & 63) == 0) { red_s[wid * 2] = sv; red_s[wid * 2 + 1] = sq; }
  __syncthreads();
  if (tid == 0) {
    double S = 0.0, Q = 0.0;
#pragma unroll
    for (int w = 0; w < 4; ++w) { S += red_s[w * 2]; Q += red_s[w * 2 + 1]; }
    stats[b * 2] = S;
    stats[b * 2 + 1] = Q;
  }
}

// K14: reduce stats -> mean/var -> bn -> logits -> log_softmax. One block.
__global__ void __launch_bounds__(1024) k_head(const float* __restrict__ fused,
                                               const double* __restrict__ stats,
                                               const float* __restrict__ gamma,
                                               const float* __restrict__ beta,
                                               const float* __restrict__ clsw,
                                               const float* __restrict__ clsb,
                                               float* __restrict__ out) {
  __shared__ double redS[16], redQ[16];
  __shared__ float cls_s[600];
  __shared__ float cb_s[3];
  __shared__ float mr_s[2];
  const int tid = threadIdx.x;
  if (tid < 600) cls_s[tid] = clsw[tid];
  if (tid < 3) cb_s[tid] = clsb[tid];
  double s = 0.0, q = 0.0;
  if (tid < 512) { s = stats[2 * tid]; q = stats[2 * tid + 1]; }
#pragma unroll
  for (int off = 32; off > 0; off >>= 1) {
    s += __shfl_down(s, off);
    q += __shfl_down(q, off);
  }
  const int wid = tid >> 6;
  if ((tid & 63) == 0) { redS[wid] = s; redQ[wid] = q; }
  __syncthreads();
  if (tid == 0) {
    double S = 0.0, Q = 0.0;
#pragma unroll
    for (int w = 0; w < 16; ++w) { S += redS[w]; Q += redQ[w]; }
    const double mean = S / 102400.0;
    const double var = Q / 102400.0 - mean * mean;
    mr_s[0] = (float)mean;
    mr_s[1] = (float)(1.0 / sqrt(var + 1e-5));
  }
  __syncthreads();
  if (tid < 512) {
    const float mean = mr_s[0], rsig = mr_s[1];
    const float ga = gamma[0], be = beta[0];
    const float* fr = fused + tid * 200;
    float l0 = cb_s[0], l1 = cb_s[1], l2 = cb_s[2];
    for (int j = 0; j < 200; ++j) {
      const float bn = (fr[j] - mean) * rsig * ga + be;
      l0 = fmaf(bn, cls_s[j], l0);
      l1 = fmaf(bn, cls_s[200 + j], l1);
      l2 = fmaf(bn, cls_s[400 + j], l2);
    }
    const float m = fmaxf(l0, fmaxf(l1, l2));
    const float lse = m + logf(expf(l0 - m) + expf(l1 - m) + expf(l2 - m));
    out[tid * 3 + 0] = l0 - lse;
    out[tid * 3 + 1] = l1 - lse;
    out[tid * 3 + 2] = l2 - lse;
  }
}

extern "C" void kernel_launch(void* const* d_in, const int* in_sizes, int n_in,
                              void* d_out, int out_size, void* d_ws, size_t ws_size,
                              hipStream_t stream) {
  (void)in_sizes; (void)n_in; (void)out_size; (void)ws_size;
  const float* x     = (const float*)d_in[0];
  const float* wih   = (const float*)d_in[1];
  const float* whh   = (const float*)d_in[2];
  const float* bih   = (const float*)d_in[3];
  const float* bhh   = (const float*)d_in[4];
  const float* sc_w  = (const float*)d_in[5];
  const float* sc_b  = (const float*)d_in[6];
  const float* c1w   = (const float*)d_in[7];
  const float* c1b   = (const float*)d_in[8];
  const float* f1w   = (const float*)d_in[9];
  const float* f1b   = (const float*)d_in[10];
  const float* k1w   = (const float*)d_in[11];
  const float* k1b   = (const float*)d_in[12];
  const float* c2w   = (const float*)d_in[13];
  const float* c2b   = (const float*)d_in[14];
  const float* f2w   = (const float*)d_in[15];
  const float* f2b   = (const float*)d_in[16];
  const float* k2w   = (const float*)d_in[17];
  const float* k2b   = (const float*)d_in[18];
  const float* gamma = (const float*)d_in[19];
  const float* beta  = (const float*)d_in[20];
  const float* clsw  = (const float*)d_in[21];
  const float* clsb  = (const float*)d_in[22];
  float* out = (float*)d_out;
  float* ws = (float*)d_ws;

  float* pre   = ws + OFF_PRE;
  float* hl    = ws + OFF_HL;
  float* hseq  = ws + OFF_HSEQ;
  float* xin1  = ws + OFF_XIN1;
  float* cbuf  = ws + OFF_C;
  float* s4    = ws + OFF_S4;
  float* xin2  = ws + OFF_XIN2;
  float* out2  = ws + OFF_OUT2;
  float* out3  = ws + OFF_OUT3;
  float* fused = ws + OFF_FUSED;
  double* stats = (double*)(ws + OFF_STATS);

  k_pregate<<<512, 256, 0, stream>>>(x, wih, bih, bhh, pre);
  k_lstm<<<LSTM_NCH, 64, 0, stream>>>(pre, whh, hseq);
  k_sconv<<<(TT * 20 + 255) / 256, 256, 0, stream>>>(hseq, sc_w, sc_b, xin1);
  // hr module 1
  k_lif3<<<LIF_NCH, 64, 0, stream>>>(xin1, hl);
  k_conv60<<<(TT * 20 + 255) / 256, 256, 0, stream>>>(hl, c1w, c1b, cbuf);
  k_lifseq<<<LIF_NCH, 64, 0, stream>>>(cbuf, s4);
  k_fcskip<20><<<(TT * 20 + 255) / 256, 256, 0, stream>>>(s4, xin1, f1w, f1b, k1w, k1b, xin2);
  // hr module 2
  k_lif3<<<LIF_NCH, 64, 0, stream>>>(xin2, hl);
  k_conv60<<<(TT * 20 + 255) / 256, 256, 0, stream>>>(hl, c2w, c2b, cbuf);
  k_lifseq<<<LIF_NCH, 64, 0, stream>>>(cbuf, s4);
  k_fcskip<10><<<(TT * 10 + 255) / 256, 256, 0, stream>>>(s4, xin2, f2w, f2b, k2w, k2b, out2);
  // final LIF over batch axis + head
  k_flif<<<(FB_NCH * 1000 + 255) / 256, 256, 0, stream>>>(out2, out3);
  k_fused<<<512, 256, 0, stream>>>(out3, fused, stats);
  k_head<<<1, 1024, 0, stream>>>(fused, stats, gamma, beta, clsw, clsb, out);
}

// Round 6
// 328.704 us; speedup vs baseline: 63.7969x; 1.0234x over previous
//
#include <hip/hip_runtime.h>
#include <math.h>

// ---------------------------------------------------------------------------
// HRSNN. R6: each hr_module fused into ONE kernel (sconv + lif3 + conv60 +
// lifseq + fcskip, all staged in LDS per 64-step chunk). Removes 7 launches
// and ~50MB of intermediate global traffic. All FP formulas / accumulation
// orders / warm-up lengths (32 per LIF stage) are unchanged -> bit-identical
// outputs (absmax pinned at 0.125 since R1). LSTM warm-up 128->96 (residue
// ~2^-74 << 2^-24 merge threshold; chunked-merge validated in R3/R4/R5).
// ---------------------------------------------------------------------------

namespace {
constexpr int TT = 51200;  // B*T
constexpr double TAU1d = 1.2231301601484298;  // exp(-1.5)+1
constexpr double TAU2d = 1.3678794411714423;  // exp(-1.0)+1  (== TAU4)
constexpr double TAU3d = 1.4493289641172216;  // exp(-0.8)+1

constexpr int LSTM_L = 32, LSTM_W = 96, LSTM_NCH = TT / LSTM_L;  // 1600
constexpr int HRL = 64;                  // hr-module output chunk length
constexpr int HR_NCH = TT / HRL;         // 800
constexpr int FB_L = 32, FB_W = 32, FB_NCH = 512 / FB_L;  // 16

// workspace layout (float offsets)
constexpr size_t OFF_PRE   = 0;         // 51200*40 (+320 over-read pad)
constexpr size_t OFF_HSEQ  = 2048320;   // 51200*10
constexpr size_t OFF_XIN2  = 3072000;   // 51200*20
constexpr size_t OFF_OUT2  = 4096000;   // 51200*10
constexpr size_t OFF_OUT3  = 4608320;   // 512*100*10 (starts past out2 pad)
constexpr size_t OFF_FUSED = 5120320;   // 512*200
constexpr size_t OFF_STATS = 5222720;   // 512*2 doubles (8-byte aligned)
}  // namespace

__device__ __forceinline__ float rcp_nr(float d) {
  float r = __builtin_amdgcn_rcpf(d);
  return r * (2.0f - d * r);  // one Newton step: ~1ulp
}

// K1: pregate[(b*100+tt)*40+l] = sum_c x[b][c][tt]*wih[l][c] + bih[l]+bhh[l]
__global__ void __launch_bounds__(256) k_pregate(const float* __restrict__ x,
                                                 const float* __restrict__ wih,
                                                 const float* __restrict__ bih,
                                                 const float* __restrict__ bhh,
                                                 float* __restrict__ pre) {
  __shared__ __align__(16) float xs[6400];   // xs[c*100+tt]
  __shared__ __align__(16) float wT[2560];   // wT[c*40+l]
  __shared__ float bl[40];
  const int b = blockIdx.x;
  const int tid = threadIdx.x;
  for (int i = tid; i < 6400; i += 256) xs[i] = x[b * 6400 + i];  // coalesced
  for (int i = tid; i < 2560; i += 256) {
    const int c = i / 40;
    const int l = i - c * 40;
    wT[i] = wih[l * 64 + c];
  }
  if (tid < 40) bl[tid] = bih[tid] + bhh[tid];
  __syncthreads();
  if (tid >= 250) return;              // 25 tt-tiles x 10 l-tiles
  const int ttile = tid / 10;
  const int ltile = tid - ttile * 10;
  const int tt0 = ttile * 4;
  const int l0 = ltile * 4;
  float acc[4][4];
#pragma unroll
  for (int i = 0; i < 4; ++i)
#pragma unroll
    for (int j = 0; j < 4; ++j) acc[i][j] = bl[l0 + j];
#pragma unroll 8
  for (int c = 0; c < 64; ++c) {
    const float4 wv = *(const float4*)&wT[c * 40 + l0];
    const float4 xv = *(const float4*)&xs[c * 100 + tt0];
    const float xa[4] = {xv.x, xv.y, xv.z, xv.w};
    const float wa[4] = {wv.x, wv.y, wv.z, wv.w};
#pragma unroll
    for (int i = 0; i < 4; ++i)
#pragma unroll
      for (int j = 0; j < 4; ++j) acc[i][j] = fmaf(xa[i], wa[j], acc[i][j]);
  }
#pragma unroll
  for (int i = 0; i < 4; ++i) {
    float4 o;
    o.x = acc[i][0]; o.y = acc[i][1]; o.z = acc[i][2]; o.w = acc[i][3];
    *(float4*)&pre[(b * 100 + tt0 + i) * 40 + l0] = o;
  }
}

// K2: chunk-parallel LSTM (warm-up LSTM_W from (0,0) -> bit-exact merge).
__global__ void __launch_bounds__(64) k_lstm(const float* __restrict__ pre,
                                             const float* __restrict__ whh,
                                             float* __restrict__ hseq) {
  const int lane = threadIdx.x;
  const int l = lane < 40 ? lane : 0;
  float wh[10];
#pragma unroll
  for (int j = 0; j < 10; ++j) wh[j] = whh[l * 10 + j];
  const int jm = lane % 10;
  const bool is_g = (l >= 20) & (l < 30);
  const float sel = is_g ? 2.0f : -1.0f;
  const int outstart = blockIdx.x * LSTM_L;
  const int start = (outstart >= LSTM_W) ? outstart - LSTM_W : 0;  // mult of 32
  const int end = outstart + LSTM_L;
  float cst = 0.0f;
  float h[10];
#pragma unroll
  for (int j = 0; j < 10; ++j) h[j] = 0.0f;
  float pbuf[8];
#pragma unroll
  for (int i = 0; i < 8; ++i) pbuf[i] = pre[(start + i) * 40 + l];
#pragma unroll 8
  for (int t = start; t < end; ++t) {
    float g = pbuf[t & 7];
    pbuf[t & 7] = pre[(t + 8) * 40 + l];  // last chunk over-reads into pad
#pragma unroll
    for (int j = 0; j < 10; ++j) g = fmaf(h[j], wh[j], g);
    const float e = __expf(sel * g);
    const float r = rcp_nr(1.0f + e);
    const float act = is_g ? (1.0f - 2.0f * r) : r;
    const float ai = __shfl(act, jm);
    const float af = __shfl(act, jm + 10);
    const float ag = __shfl(act, jm + 20);
    const float ao = __shfl(act, jm + 30);
    cst = af * cst + ai * ag;
    const float hn = ao * (1.0f - 2.0f * rcp_nr(__expf(2.0f * cst) + 1.0f));
    if ((lane < 10) & (t >= outstart)) hseq[t * 10 + lane] = hn;
#pragma unroll
    for (int j = 0; j < 10; ++j)
      h[j] = __uint_as_float(__builtin_amdgcn_readlane(__float_as_uint(hn), j));
  }
}

// K3/K4: fused hr_module. One wave per HRL-step output chunk.
//   P1: xin (MODE0: sconv(hseq); MODE1: copy from global) over [s1,end)
//   P2: lif3 scan from s1 (=s2-32, clamped) -> hl over [s2,end)
//   P3: conv60 pointwise -> c over [s2,end)
//   P4: lifseq scan from s2 (=outstart-32, clamped) -> s4 over [outstart,end)
//   P5: fcskip -> outp
// Every FP op identical in formula+order to the unfused R5 kernels.
template <int MODE, int O>
__global__ void __launch_bounds__(64) k_hr(const float* __restrict__ src,
                                           const float* __restrict__ sw,
                                           const float* __restrict__ sb,
                                           const float* __restrict__ cw,
                                           const float* __restrict__ cb,
                                           const float* __restrict__ fw,
                                           const float* __restrict__ fb,
                                           const float* __restrict__ skw,
                                           const float* __restrict__ skb,
                                           float* __restrict__ outp) {
  __shared__ float xin_s[128 * 20];
  __shared__ float hl_s[96 * 60];
  __shared__ float c_s[96 * 20];
  __shared__ float s4_s[HRL * 20];
  __shared__ float cw_s[1200];
  __shared__ float cb_s[20];
  __shared__ float fw_s[O * 20];
  __shared__ float fb_s[O];
  __shared__ float skw_s[O * 20];
  __shared__ float skb_s[O];
  __shared__ float sw_s[200];
  __shared__ float sb_s[20];

  const int tid = threadIdx.x;
  const int outstart = blockIdx.x * HRL;
  const int end = outstart + HRL;
  const int s2 = (outstart >= 32) ? outstart - 32 : 0;
  const int s1 = (s2 >= 32) ? s2 - 32 : 0;
  const int n1 = end - s1;  // <=128
  const int n2 = end - s2;  // <=96

  for (int i = tid; i < 1200; i += 64) cw_s[i] = cw[i];
  for (int i = tid; i < O * 20; i += 64) { fw_s[i] = fw[i]; skw_s[i] = skw[i]; }
  if (tid < O) { fb_s[tid] = fb[tid]; skb_s[tid] = skb[tid]; }
  if (tid < 20) cb_s[tid] = cb[tid];
  if (MODE == 0) {
    for (int i = tid; i < 200; i += 64) sw_s[i] = sw[i];
    if (tid < 20) sb_s[tid] = sb[tid];
  }
  __syncthreads();

  // P1: module input
  if (MODE == 0) {
    for (int idx = tid; idx < n1 * 20; idx += 64) {
      const int rel = idx / 20;
      const int o = idx - rel * 20;
      const float* hp = src + (s1 + rel) * 10;
      const float* wp = sw_s + o * 10;
      float acc = sb_s[o];
#pragma unroll
      for (int j = 0; j < 10; ++j) acc = fmaf(hp[j], wp[j], acc);
      xin_s[idx] = acc;
    }
  } else {
    for (int idx = tid; idx < n1 * 20; idx += 64) xin_s[idx] = src[s1 * 20 + idx];
  }
  __syncthreads();

  // P2: lif3 scan (60 chains)
  {
    const int cid = tid < 60 ? tid : 0;
    const int f = cid / 3;
    const int k = cid - f * 3;
    const float tau = (k == 0) ? (float)TAU1d : (k == 1) ? (float)TAU2d : (float)TAU3d;
    const float rt = 1.0f / tau;
    const float th = (k == 0) ? 0.14f : (k == 1) ? 0.08f : 0.06f;
    float v = 0.0f;
#pragma unroll 8
    for (int t = s1; t < end; ++t) {
      const float x = xin_s[(t - s1) * 20 + f];
      v = fmaf(x - v, rt, v);
      const float sp = (v - th >= 0.0f) ? 1.0f : 0.0f;
      if ((tid < 60) & (t >= s2)) hl_s[(t - s2) * 60 + tid] = sp;
      v = (sp != 0.0f) ? 0.0f : v;
    }
  }
  __syncthreads();

  // P3: conv60
  for (int idx = tid; idx < n2 * 20; idx += 64) {
    const int rel = idx / 20;
    const int o = idx - rel * 20;
    const float* hp = hl_s + rel * 60;
    const float* wp = cw_s + o * 60;
    float acc = cb_s[o];
#pragma unroll
    for (int d = 0; d < 60; ++d) acc = fmaf(hp[d], wp[d], acc);
    c_s[idx] = acc;
  }
  __syncthreads();

  // P4: lifseq scan (20 chains)
  {
    const int f = tid < 20 ? tid : 0;
    const float rt = 1.0f / (float)TAU2d;
    float v = 0.0f;
#pragma unroll 8
    for (int t = s2; t < end; ++t) {
      const float x = c_s[(t - s2) * 20 + f];
      v = fmaf(x - v, rt, v);
      const float sp = (v - 0.08f >= 0.0f) ? 1.0f : 0.0f;
      if ((tid < 20) & (t >= outstart)) s4_s[(t - outstart) * 20 + tid] = sp;
      v = (sp != 0.0f) ? 0.0f : v;
    }
  }
  __syncthreads();

  // P5: fcskip
  for (int idx = tid; idx < HRL * O; idx += 64) {
    const int rel = idx / O;
    const int o = idx - rel * O;
    const float* s = s4_s + rel * 20;
    const float* xi = xin_s + (outstart - s1 + rel) * 20;
    const float* fwp = fw_s + o * 20;
    const float* swp = skw_s + o * 20;
    float acc = fb_s[o] + skb_s[o];
#pragma unroll
    for (int j = 0; j < 20; ++j) acc = fmaf(s[j], fwp[j], fmaf(xi[j], swp[j], acc));
    outp[(outstart + rel) * O + o] = acc;
  }
}

// K5: final LIF over batch axis: 1000 chains, chunked over b (L=W=32).
__global__ void __launch_bounds__(256) k_flif(const float* __restrict__ out2,
                                              float* __restrict__ out3) {
  const int idx = blockIdx.x * 256 + threadIdx.x;
  if (idx >= FB_NCH * 1000) return;
  const int chunk = idx / 1000;
  const int chain = idx - chunk * 1000;
  const float rt = 1.0f / (float)TAU2d;
  const int outstart = chunk * FB_L;
  const int start = (outstart >= FB_W) ? outstart - FB_W : 0;
  const int end = outstart + FB_L;
  float v = 0.0f;
  float xb[4];
#pragma unroll
  for (int i = 0; i < 4; ++i) xb[i] = out2[(start + i) * 1000 + chain];
#pragma unroll 4
  for (int b = start; b < end; ++b) {
    const float x = xb[b & 3];
    xb[b & 3] = out2[(b + 4) * 1000 + chain];  // over-read into pad (dead)
    v = fmaf(x - v, rt, v);
    const float sp = (v - 0.08f >= 0.0f) ? 1.0f : 0.0f;
    if (b >= outstart) out3[b * 1000 + chain] = sp;
    v = (sp != 0.0f) ? 0.0f : v;
  }
}

// K6: dp -> avg -> fused; per-block (per-b) partial sum/sumsq in double.
__global__ void __launch_bounds__(256) k_fused(const float* __restrict__ out3,
                                               float* __restrict__ fused,
                                               double* __restrict__ stats) {
  __shared__ float dp_s[200];
  __shared__ float avg_s[20];
  __shared__ double red_s[8];
  const int b = blockIdx.x;
  const int tid = threadIdx.x;
  if (tid < 200) {
    const int f = tid / 20;
    const int seg = tid - f * 20;
    const float* base = out3 + b * 1000 + seg * 50 + f;
    dp_s[tid] = ((base[30] + base[40]) - (base[0] + base[10])) * 0.5f;
  }
  __syncthreads();
  if (tid < 20) {
    float s = 0.0f;
#pragma unroll
    for (int f = 0; f < 10; ++f) s += dp_s[f * 20 + tid];
    avg_s[tid] = s / 10.0f;
  }
  __syncthreads();
  float val = 0.0f;
  if (tid < 200) {
    val = dp_s[tid] * avg_s[tid % 20];
    fused[b * 200 + tid] = val;
  }
  double sv = (double)val, sq = (double)val * (double)val;
#pragma unroll
  for (int off = 32; off > 0; off >>= 1) {
    sv += __shfl_down(sv, off);
    sq += __shfl_down(sq, off);
  }
  const int wid = tid >> 6;
  if ((tid & 63) == 0) { red_s[wid * 2] = sv; red_s[wid * 2 + 1] = sq; }
  __syncthreads();
  if (tid == 0) {
    double S = 0.0, Q = 0.0;
#pragma unroll
    for (int w = 0; w < 4; ++w) { S += red_s[w * 2]; Q += red_s[w * 2 + 1]; }
    stats[b * 2] = S;
    stats[b * 2 + 1] = Q;
  }
}

// K7: reduce stats -> mean/var -> bn -> logits -> log_softmax. One block.
__global__ void __launch_bounds__(1024) k_head(const float* __restrict__ fused,
                                               const double* __restrict__ stats,
                                               const float* __restrict__ gamma,
                                               const float* __restrict__ beta,
                                               const float* __restrict__ clsw,
                                               const float* __restrict__ clsb,
                                               float* __restrict__ out) {
  __shared__ double redS[16], redQ[16];
  __shared__ float cls_s[600];
  __shared__ float cb_s[3];
  __shared__ float mr_s[2];
  const int tid = threadIdx.x;
  if (tid < 600) cls_s[tid] = clsw[tid];
  if (tid < 3) cb_s[tid] = clsb[tid];
  double s = 0.0, q = 0.0;
  if (tid < 512) { s = stats[2 * tid]; q = stats[2 * tid + 1]; }
#pragma unroll
  for (int off = 32; off > 0; off >>= 1) {
    s += __shfl_down(s, off);
    q += __shfl_down(q, off);
  }
  const int wid = tid >> 6;
  if ((tid & 63) == 0) { redS[wid] = s; redQ[wid] = q; }
  __syncthreads();
  if (tid == 0) {
    double S = 0.0, Q = 0.0;
#pragma unroll
    for (int w = 0; w < 16; ++w) { S += redS[w]; Q += redQ[w]; }
    const double mean = S / 102400.0;
    const double var = Q / 102400.0 - mean * mean;
    mr_s[0] = (float)mean;
    mr_s[1] = (float)(1.0 / sqrt(var + 1e-5));
  }
  __syncthreads();
  if (tid < 512) {
    const float mean = mr_s[0], rsig = mr_s[1];
    const float ga = gamma[0], be = beta[0];
    const float* fr = fused + tid * 200;
    float l0 = cb_s[0], l1 = cb_s[1], l2 = cb_s[2];
    for (int j = 0; j < 200; ++j) {
      const float bn = (fr[j] - mean) * rsig * ga + be;
      l0 = fmaf(bn, cls_s[j], l0);
      l1 = fmaf(bn, cls_s[200 + j], l1);
      l2 = fmaf(bn, cls_s[400 + j], l2);
    }
    const float m = fmaxf(l0, fmaxf(l1, l2));
    const float lse = m + logf(expf(l0 - m) + expf(l1 - m) + expf(l2 - m));
    out[tid * 3 + 0] = l0 - lse;
    out[tid * 3 + 1] = l1 - lse;
    out[tid * 3 + 2] = l2 - lse;
  }
}

extern "C" void kernel_launch(void* const* d_in, const int* in_sizes, int n_in,
                              void* d_out, int out_size, void* d_ws, size_t ws_size,
                              hipStream_t stream) {
  (void)in_sizes; (void)n_in; (void)out_size; (void)ws_size;
  const float* x     = (const float*)d_in[0];
  const float* wih   = (const float*)d_in[1];
  const float* whh   = (const float*)d_in[2];
  const float* bih   = (const float*)d_in[3];
  const float* bhh   = (const float*)d_in[4];
  const float* sc_w  = (const float*)d_in[5];
  const float* sc_b  = (const float*)d_in[6];
  const float* c1w   = (const float*)d_in[7];
  const float* c1b   = (const float*)d_in[8];
  const float* f1w   = (const float*)d_in[9];
  const float* f1b   = (const float*)d_in[10];
  const float* k1w   = (const float*)d_in[11];
  const float* k1b   = (const float*)d_in[12];
  const float* c2w   = (const float*)d_in[13];
  const float* c2b   = (const float*)d_in[14];
  const float* f2w   = (const float*)d_in[15];
  const float* f2b   = (const float*)d_in[16];
  const float* k2w   = (const float*)d_in[17];
  const float* k2b   = (const float*)d_in[18];
  const float* gamma = (const float*)d_in[19];
  const float* beta  = (const float*)d_in[20];
  const float* clsw  = (const float*)d_in[21];
  const float* clsb  = (const float*)d_in[22];
  float* out = (float*)d_out;
  float* ws = (float*)d_ws;

  float* pre   = ws + OFF_PRE;
  float* hseq  = ws + OFF_HSEQ;
  float* xin2  = ws + OFF_XIN2;
  float* out2  = ws + OFF_OUT2;
  float* out3  = ws + OFF_OUT3;
  float* fused = ws + OFF_FUSED;
  double* stats = (double*)(ws + OFF_STATS);

  k_pregate<<<512, 256, 0, stream>>>(x, wih, bih, bhh, pre);
  k_lstm<<<LSTM_NCH, 64, 0, stream>>>(pre, whh, hseq);
  k_hr<0, 20><<<HR_NCH, 64, 0, stream>>>(hseq, sc_w, sc_b, c1w, c1b, f1w, f1b,
                                         k1w, k1b, xin2);
  k_hr<1, 10><<<HR_NCH, 64, 0, stream>>>(xin2, nullptr, nullptr, c2w, c2b,
                                         f2w, f2b, k2w, k2b, out2);
  k_flif<<<(FB_NCH * 1000 + 255) / 256, 256, 0, stream>>>(out2, out3);
  k_fused<<<512, 256, 0, stream>>>(out3, fused, stats);
  k_head<<<1, 1024, 0, stream>>>(fused, stats, gamma, beta, clsw, clsb, out);
}

// Round 7
// 269.840 us; speedup vs baseline: 77.7138x; 1.2181x over previous
//
#include <hip/hip_runtime.h>
#include <math.h>

// ---------------------------------------------------------------------------
// HRSNN. R7: fused hr_module rebuilt for throughput. R6's k_hr was
// LDS-issue-bound on a single wave (64 thr, scalar ds_read_b32, 92us,
// VALUBusy 11%, 723k bank-conflict cycles). Now: 256 threads (4 waves) for
// the parallel phases, ds_read_b128/float2 vector LDS accesses everywhere,
// hseq chunk staged to LDS. Scans (inherently serial) run on wave 0 only.
// Per-output FMA order unchanged -> bit-identical outputs (absmax 0.125).
// ---------------------------------------------------------------------------

namespace {
constexpr int TT = 51200;  // B*T
constexpr double TAU1d = 1.2231301601484298;  // exp(-1.5)+1
constexpr double TAU2d = 1.3678794411714423;  // exp(-1.0)+1  (== TAU4)
constexpr double TAU3d = 1.4493289641172216;  // exp(-0.8)+1

constexpr int LSTM_L = 32, LSTM_W = 96, LSTM_NCH = TT / LSTM_L;  // 1600
constexpr int HRL = 64;                  // hr-module output chunk length
constexpr int HR_NCH = TT / HRL;         // 800
constexpr int FB_L = 32, FB_W = 32, FB_NCH = 512 / FB_L;  // 16

// workspace layout (float offsets)
constexpr size_t OFF_PRE   = 0;         // 51200*40 (+320 over-read pad)
constexpr size_t OFF_HSEQ  = 2048320;   // 51200*10
constexpr size_t OFF_XIN2  = 3072000;   // 51200*20
constexpr size_t OFF_OUT2  = 4096000;   // 51200*10
constexpr size_t OFF_OUT3  = 4608320;   // 512*100*10
constexpr size_t OFF_FUSED = 5120320;   // 512*200
constexpr size_t OFF_STATS = 5222720;   // 512*2 doubles (8-byte aligned)
}  // namespace

__device__ __forceinline__ float rcp_nr(float d) {
  float r = __builtin_amdgcn_rcpf(d);
  return r * (2.0f - d * r);  // one Newton step: ~1ulp
}

// K1: pregate[(b*100+tt)*40+l] = sum_c x[b][c][tt]*wih[l][c] + bih[l]+bhh[l]
__global__ void __launch_bounds__(256) k_pregate(const float* __restrict__ x,
                                                 const float* __restrict__ wih,
                                                 const float* __restrict__ bih,
                                                 const float* __restrict__ bhh,
                                                 float* __restrict__ pre) {
  __shared__ __align__(16) float xs[6400];   // xs[c*100+tt]
  __shared__ __align__(16) float wT[2560];   // wT[c*40+l]
  __shared__ float bl[40];
  const int b = blockIdx.x;
  const int tid = threadIdx.x;
  for (int i = tid; i < 6400; i += 256) xs[i] = x[b * 6400 + i];  // coalesced
  for (int i = tid; i < 2560; i += 256) {
    const int c = i / 40;
    const int l = i - c * 40;
    wT[i] = wih[l * 64 + c];
  }
  if (tid < 40) bl[tid] = bih[tid] + bhh[tid];
  __syncthreads();
  if (tid >= 250) return;              // 25 tt-tiles x 10 l-tiles
  const int ttile = tid / 10;
  const int ltile = tid - ttile * 10;
  const int tt0 = ttile * 4;
  const int l0 = ltile * 4;
  float acc[4][4];
#pragma unroll
  for (int i = 0; i < 4; ++i)
#pragma unroll
    for (int j = 0; j < 4; ++j) acc[i][j] = bl[l0 + j];
#pragma unroll 8
  for (int c = 0; c < 64; ++c) {
    const float4 wv = *(const float4*)&wT[c * 40 + l0];
    const float4 xv = *(const float4*)&xs[c * 100 + tt0];
    const float xa[4] = {xv.x, xv.y, xv.z, xv.w};
    const float wa[4] = {wv.x, wv.y, wv.z, wv.w};
#pragma unroll
    for (int i = 0; i < 4; ++i)
#pragma unroll
      for (int j = 0; j < 4; ++j) acc[i][j] = fmaf(xa[i], wa[j], acc[i][j]);
  }
#pragma unroll
  for (int i = 0; i < 4; ++i) {
    float4 o;
    o.x = acc[i][0]; o.y = acc[i][1]; o.z = acc[i][2]; o.w = acc[i][3];
    *(float4*)&pre[(b * 100 + tt0 + i) * 40 + l0] = o;
  }
}

// K2: chunk-parallel LSTM (warm-up LSTM_W from (0,0) -> bit-exact merge).
__global__ void __launch_bounds__(64) k_lstm(const float* __restrict__ pre,
                                             const float* __restrict__ whh,
                                             float* __restrict__ hseq) {
  const int lane = threadIdx.x;
  const int l = lane < 40 ? lane : 0;
  float wh[10];
#pragma unroll
  for (int j = 0; j < 10; ++j) wh[j] = whh[l * 10 + j];
  const int jm = lane % 10;
  const bool is_g = (l >= 20) & (l < 30);
  const float sel = is_g ? 2.0f : -1.0f;
  const int outstart = blockIdx.x * LSTM_L;
  const int start = (outstart >= LSTM_W) ? outstart - LSTM_W : 0;  // mult of 32
  const int end = outstart + LSTM_L;
  float cst = 0.0f;
  float h[10];
#pragma unroll
  for (int j = 0; j < 10; ++j) h[j] = 0.0f;
  float pbuf[8];
#pragma unroll
  for (int i = 0; i < 8; ++i) pbuf[i] = pre[(start + i) * 40 + l];
#pragma unroll 8
  for (int t = start; t < end; ++t) {
    float g = pbuf[t & 7];
    pbuf[t & 7] = pre[(t + 8) * 40 + l];  // last chunk over-reads into pad
#pragma unroll
    for (int j = 0; j < 10; ++j) g = fmaf(h[j], wh[j], g);
    const float e = __expf(sel * g);
    const float r = rcp_nr(1.0f + e);
    const float act = is_g ? (1.0f - 2.0f * r) : r;
    const float ai = __shfl(act, jm);
    const float af = __shfl(act, jm + 10);
    const float ag = __shfl(act, jm + 20);
    const float ao = __shfl(act, jm + 30);
    cst = af * cst + ai * ag;
    const float hn = ao * (1.0f - 2.0f * rcp_nr(__expf(2.0f * cst) + 1.0f));
    if ((lane < 10) & (t >= outstart)) hseq[t * 10 + lane] = hn;
#pragma unroll
    for (int j = 0; j < 10; ++j)
      h[j] = __uint_as_float(__builtin_amdgcn_readlane(__float_as_uint(hn), j));
  }
}

// K3/K4: fused hr_module, 256 threads. Phases:
//   stage: weights + (MODE0: hseq chunk | MODE1: xin chunk) -> LDS (float4)
//   P1 (MODE0 only): sconv -> xin_s            [all 256 thr, float2 LDS]
//   P2: lif3 scan -> hl_s                      [wave 0, 60 lanes]
//   P3: conv60 -> c_s                          [all 256 thr, ds_read_b128]
//   P4: lifseq scan -> s4_s                    [wave 0, 20 lanes]
//   P5: fcskip -> global                       [all 256 thr, ds_read_b128]
// Per-output accumulation order identical to R6 -> bit-identical results.
template <int MODE, int O>
__global__ void __launch_bounds__(256) k_hr(const float* __restrict__ src,
                                            const float* __restrict__ sw,
                                            const float* __restrict__ sb,
                                            const float* __restrict__ cw,
                                            const float* __restrict__ cb,
                                            const float* __restrict__ fw,
                                            const float* __restrict__ fb,
                                            const float* __restrict__ skw,
                                            const float* __restrict__ skb,
                                            float* __restrict__ outp) {
  __shared__ __align__(16) float xin_s[128 * 20];
  __shared__ __align__(16) float hs_s[MODE == 0 ? 128 * 10 : 4];
  __shared__ __align__(16) float hl_s[96 * 60];
  __shared__ __align__(16) float c_s[96 * 20];
  __shared__ __align__(16) float s4_s[HRL * 20];
  __shared__ __align__(16) float cw_s[1200];
  __shared__ __align__(16) float fw_s[O * 20];
  __shared__ __align__(16) float skw_s[O * 20];
  __shared__ __align__(16) float sw_s[MODE == 0 ? 200 : 4];
  __shared__ float cb_s[20];
  __shared__ float fb_s[O];
  __shared__ float skb_s[O];
  __shared__ float sb_s[20];

  const int tid = threadIdx.x;
  const int outstart = blockIdx.x * HRL;
  const int end = outstart + HRL;
  const int s2 = (outstart >= 32) ? outstart - 32 : 0;
  const int s1 = (s2 >= 32) ? s2 - 32 : 0;
  const int n1 = end - s1;  // <=128
  const int n2 = end - s2;  // <=96

  // ---- stage (float4) ----
  for (int i = tid; i < 300; i += 256)
    ((float4*)cw_s)[i] = ((const float4*)cw)[i];
  for (int i = tid; i < O * 5; i += 256) {
    ((float4*)fw_s)[i] = ((const float4*)fw)[i];
    ((float4*)skw_s)[i] = ((const float4*)skw)[i];
  }
  if (tid < O) { fb_s[tid] = fb[tid]; skb_s[tid] = skb[tid]; }
  if (tid >= 32 && tid < 52) cb_s[tid - 32] = cb[tid - 32];
  if (MODE == 0) {
    for (int i = tid; i < 50; i += 256)
      ((float4*)sw_s)[i] = ((const float4*)sw)[i];
    if (tid >= 64 && tid < 84) sb_s[tid - 64] = sb[tid - 64];
    // hseq chunk: n1*10 floats, contiguous, 16B aligned (s1 mult of 32)
    const float4* gsrc = (const float4*)(src + (size_t)s1 * 10);
    for (int i = tid; i < n1 * 10 / 4; i += 256) ((float4*)hs_s)[i] = gsrc[i];
  } else {
    const float4* gsrc = (const float4*)(src + (size_t)s1 * 20);
    for (int i = tid; i < n1 * 5; i += 256) ((float4*)xin_s)[i] = gsrc[i];
  }
  __syncthreads();

  // ---- P1: sconv -> xin_s (MODE 0) ----
  if (MODE == 0) {
    for (int idx = tid; idx < n1 * 20; idx += 256) {
      const int rel = idx / 20;
      const int o = idx - rel * 20;
      const float* hp = hs_s + rel * 10;
      const float* wp = sw_s + o * 10;
      float acc = sb_s[o];
#pragma unroll
      for (int j2 = 0; j2 < 5; ++j2) {
        const float2 h = *(const float2*)&hp[j2 * 2];
        const float2 w = *(const float2*)&wp[j2 * 2];
        acc = fmaf(h.x, w.x, acc);
        acc = fmaf(h.y, w.y, acc);
      }
      xin_s[idx] = acc;
    }
    __syncthreads();
  }

  // ---- P2: lif3 scan (wave 0, 60 chains) ----
  if (tid < 64) {
    const int cid = tid < 60 ? tid : 0;
    const int f = cid / 3;
    const int k = cid - f * 3;
    const float tau = (k == 0) ? (float)TAU1d : (k == 1) ? (float)TAU2d : (float)TAU3d;
    const float rt = 1.0f / tau;
    const float th = (k == 0) ? 0.14f : (k == 1) ? 0.08f : 0.06f;
    float v = 0.0f;
#pragma unroll 8
    for (int t = s1; t < end; ++t) {
      const float x = xin_s[(t - s1) * 20 + f];
      v = fmaf(x - v, rt, v);
      const float sp = (v - th >= 0.0f) ? 1.0f : 0.0f;
      if ((tid < 60) & (t >= s2)) hl_s[(t - s2) * 60 + tid] = sp;
      v = (sp != 0.0f) ? 0.0f : v;
    }
  }
  __syncthreads();

  // ---- P3: conv60 -> c_s (ds_read_b128; rows are 240B, 16B aligned) ----
  for (int idx = tid; idx < n2 * 20; idx += 256) {
    const int rel = idx / 20;
    const int o = idx - rel * 20;
    const float* hp = hl_s + rel * 60;
    const float* wp = cw_s + o * 60;
    float acc = cb_s[o];
#pragma unroll
    for (int d4 = 0; d4 < 15; ++d4) {
      const float4 h = *(const float4*)&hp[d4 * 4];
      const float4 w = *(const float4*)&wp[d4 * 4];
      acc = fmaf(h.x, w.x, acc);
      acc = fmaf(h.y, w.y, acc);
      acc = fmaf(h.z, w.z, acc);
      acc = fmaf(h.w, w.w, acc);
    }
    c_s[idx] = acc;
  }
  __syncthreads();

  // ---- P4: lifseq scan (wave 0, 20 chains) ----
  if (tid < 64) {
    const int f = tid < 20 ? tid : 0;
    const float rt = 1.0f / (float)TAU2d;
    float v = 0.0f;
#pragma unroll 8
    for (int t = s2; t < end; ++t) {
      const float x = c_s[(t - s2) * 20 + f];
      v = fmaf(x - v, rt, v);
      const float sp = (v - 0.08f >= 0.0f) ? 1.0f : 0.0f;
      if ((tid < 20) & (t >= outstart)) s4_s[(t - outstart) * 20 + tid] = sp;
      v = (sp != 0.0f) ? 0.0f : v;
    }
  }
  __syncthreads();

  // ---- P5: fcskip -> global (all rows 80B, 16B aligned) ----
  const int xoff = outstart - s1;
  for (int idx = tid; idx < HRL * O; idx += 256) {
    const int rel = idx / O;
    const int o = idx - rel * O;
    const float* s = s4_s + rel * 20;
    const float* xi = xin_s + (xoff + rel) * 20;
    const float* fwp = fw_s + o * 20;
    const float* swp = skw_s + o * 20;
    float acc = fb_s[o] + skb_s[o];
#pragma unroll
    for (int q = 0; q < 5; ++q) {
      const float4 sv = *(const float4*)&s[q * 4];
      const float4 xv = *(const float4*)&xi[q * 4];
      const float4 fv = *(const float4*)&fwp[q * 4];
      const float4 kv = *(const float4*)&swp[q * 4];
      acc = fmaf(sv.x, fv.x, fmaf(xv.x, kv.x, acc));
      acc = fmaf(sv.y, fv.y, fmaf(xv.y, kv.y, acc));
      acc = fmaf(sv.z, fv.z, fmaf(xv.z, kv.z, acc));
      acc = fmaf(sv.w, fv.w, fmaf(xv.w, kv.w, acc));
    }
    outp[(size_t)(outstart + rel) * O + o] = acc;
  }
}

// K5: final LIF over batch axis: 1000 chains, chunked over b (L=W=32).
__global__ void __launch_bounds__(256) k_flif(const float* __restrict__ out2,
                                              float* __restrict__ out3) {
  const int idx = blockIdx.x * 256 + threadIdx.x;
  if (idx >= FB_NCH * 1000) return;
  const int chunk = idx / 1000;
  const int chain = idx - chunk * 1000;
  const float rt = 1.0f / (float)TAU2d;
  const int outstart = chunk * FB_L;
  const int start = (outstart >= FB_W) ? outstart - FB_W : 0;
  const int end = outstart + FB_L;
  float v = 0.0f;
  float xb[4];
#pragma unroll
  for (int i = 0; i < 4; ++i) xb[i] = out2[(start + i) * 1000 + chain];
#pragma unroll 4
  for (int b = start; b < end; ++b) {
    const float x = xb[b & 3];
    xb[b & 3] = out2[(b + 4) * 1000 + chain];  // over-read harmless (unused)
    v = fmaf(x - v, rt, v);
    const float sp = (v - 0.08f >= 0.0f) ? 1.0f : 0.0f;
    if (b >= outstart) out3[b * 1000 + chain] = sp;
    v = (sp != 0.0f) ? 0.0f : v;
  }
}

// K6: dp -> avg -> fused; per-block (per-b) partial sum/sumsq in double.
__global__ void __launch_bounds__(256) k_fused(const float* __restrict__ out3,
                                               float* __restrict__ fused,
                                               double* __restrict__ stats) {
  __shared__ float dp_s[200];
  __shared__ float avg_s[20];
  __shared__ double red_s[8];
  const int b = blockIdx.x;
  const int tid = threadIdx.x;
  if (tid < 200) {
    const int f = tid / 20;
    const int seg = tid - f * 20;
    const float* base = out3 + b * 1000 + seg * 50 + f;
    dp_s[tid] = ((base[30] + base[40]) - (base[0] + base[10])) * 0.5f;
  }
  __syncthreads();
  if (tid < 20) {
    float s = 0.0f;
#pragma unroll
    for (int f = 0; f < 10; ++f) s += dp_s[f * 20 + tid];
    avg_s[tid] = s / 10.0f;
  }
  __syncthreads();
  float val = 0.0f;
  if (tid < 200) {
    val = dp_s[tid] * avg_s[tid % 20];
    fused[b * 200 + tid] = val;
  }
  double sv = (double)val, sq = (double)val * (double)val;
#pragma unroll
  for (int off = 32; off > 0; off >>= 1) {
    sv += __shfl_down(sv, off);
    sq += __shfl_down(sq, off);
  }
  const int wid = tid >> 6;
  if ((tid & 63) == 0) { red_s[wid * 2] = sv; red_s[wid * 2 + 1] = sq; }
  __syncthreads();
  if (tid == 0) {
    double S = 0.0, Q = 0.0;
#pragma unroll
    for (int w = 0; w < 4; ++w) { S += red_s[w * 2]; Q += red_s[w * 2 + 1]; }
    stats[b * 2] = S;
    stats[b * 2 + 1] = Q;
  }
}

// K7: reduce stats -> mean/var -> bn -> logits -> log_softmax. One block.
__global__ void __launch_bounds__(1024) k_head(const float* __restrict__ fused,
                                               const double* __restrict__ stats,
                                               const float* __restrict__ gamma,
                                               const float* __restrict__ beta,
                                               const float* __restrict__ clsw,
                                               const float* __restrict__ clsb,
                                               float* __restrict__ out) {
  __shared__ double redS[16], redQ[16];
  __shared__ float cls_s[600];
  __shared__ float cb_s[3];
  __shared__ float mr_s[2];
  const int tid = threadIdx.x;
  if (tid < 600) cls_s[tid] = clsw[tid];
  if (tid < 3) cb_s[tid] = clsb[tid];
  double s = 0.0, q = 0.0;
  if (tid < 512) { s = stats[2 * tid]; q = stats[2 * tid + 1]; }
#pragma unroll
  for (int off = 32; off > 0; off >>= 1) {
    s += __shfl_down(s, off);
    q += __shfl_down(q, off);
  }
  const int wid = tid >> 6;
  if ((tid & 63) == 0) { redS[wid] = s; redQ[wid] = q; }
  __syncthreads();
  if (tid == 0) {
    double S = 0.0, Q = 0.0;
#pragma unroll
    for (int w = 0; w < 16; ++w) { S += redS[w]; Q += redQ[w]; }
    const double mean = S / 102400.0;
    const double var = Q / 102400.0 - mean * mean;
    mr_s[0] = (float)mean;
    mr_s[1] = (float)(1.0 / sqrt(var + 1e-5));
  }
  __syncthreads();
  if (tid < 512) {
    const float mean = mr_s[0], rsig = mr_s[1];
    const float ga = gamma[0], be = beta[0];
    const float* fr = fused + tid * 200;
    float l0 = cb_s[0], l1 = cb_s[1], l2 = cb_s[2];
    for (int j = 0; j < 200; ++j) {
      const float bn = (fr[j] - mean) * rsig * ga + be;
      l0 = fmaf(bn, cls_s[j], l0);
      l1 = fmaf(bn, cls_s[200 + j], l1);
      l2 = fmaf(bn, cls_s[400 + j], l2);
    }
    const float m = fmaxf(l0, fmaxf(l1, l2));
    const float lse = m + logf(expf(l0 - m) + expf(l1 - m) + expf(l2 - m));
    out[tid * 3 + 0] = l0 - lse;
    out[tid * 3 + 1] = l1 - lse;
    out[tid * 3 + 2] = l2 - lse;
  }
}

extern "C" void kernel_launch(void* const* d_in, const int* in_sizes, int n_in,
                              void* d_out, int out_size, void* d_ws, size_t ws_size,
                              hipStream_t stream) {
  (void)in_sizes; (void)n_in; (void)out_size; (void)ws_size;
  const float* x     = (const float*)d_in[0];
  const float* wih   = (const float*)d_in[1];
  const float* whh   = (const float*)d_in[2];
  const float* bih   = (const float*)d_in[3];
  const float* bhh   = (const float*)d_in[4];
  const float* sc_w  = (const float*)d_in[5];
  const float* sc_b  = (const float*)d_in[6];
  const float* c1w   = (const float*)d_in[7];
  const float* c1b   = (const float*)d_in[8];
  const float* f1w   = (const float*)d_in[9];
  const float* f1b   = (const float*)d_in[10];
  const float* k1w   = (const float*)d_in[11];
  const float* k1b   = (const float*)d_in[12];
  const float* c2w   = (const float*)d_in[13];
  const float* c2b   = (const float*)d_in[14];
  const float* f2w   = (const float*)d_in[15];
  const float* f2b   = (const float*)d_in[16];
  const float* k2w   = (const float*)d_in[17];
  const float* k2b   = (const float*)d_in[18];
  const float* gamma = (const float*)d_in[19];
  const float* beta  = (const float*)d_in[20];
  const float* clsw  = (const float*)d_in[21];
  const float* clsb  = (const float*)d_in[22];
  float* out = (float*)d_out;
  float* ws = (float*)d_ws;

  float* pre   = ws + OFF_PRE;
  float* hseq  = ws + OFF_HSEQ;
  float* xin2  = ws + OFF_XIN2;
  float* out2  = ws + OFF_OUT2;
  float* out3  = ws + OFF_OUT3;
  float* fused = ws + OFF_FUSED;
  double* stats = (double*)(ws + OFF_STATS);

  k_pregate<<<512, 256, 0, stream>>>(x, wih, bih, bhh, pre);
  k_lstm<<<LSTM_NCH, 64, 0, stream>>>(pre, whh, hseq);
  k_hr<0, 20><<<HR_NCH, 256, 0, stream>>>(hseq, sc_w, sc_b, c1w, c1b, f1w, f1b,
                                          k1w, k1b, xin2);
  k_hr<1, 10><<<HR_NCH, 256, 0, stream>>>(xin2, nullptr, nullptr, c2w, c2b,
                                          f2w, f2b, k2w, k2b, out2);
  k_flif<<<(FB_NCH * 1000 + 255) / 256, 256, 0, stream>>>(out2, out3);
  k_fused<<<512, 256, 0, stream>>>(out3, fused, stats);
  k_head<<<1, 1024, 0, stream>>>(fused, stats, gamma, beta, clsw, clsb, out);
}

// Round 8
// 259.548 us; speedup vs baseline: 80.7954x; 1.0397x over previous
//
#include <hip/hip_runtime.h>
#include <math.h>

// ---------------------------------------------------------------------------
// HRSNN. R8: k_hr parallel phases restructured to kill redundant LDS traffic
// (R7 was CU-LDS-pipe-bound: ~20k LDS cycles/block). Thread = (out-channel o,
// row-group rg); weight row cached in VGPRs once; the 20 lanes sharing rg
// read the same activation row -> same-address broadcast (free). P5 results
// staged in LDS and written coalesced. Per-output accumulation order is
// bit-identical to R7 (bias first, ascending taps) -> absmax stays 0.125.
// ---------------------------------------------------------------------------

namespace {
constexpr int TT = 51200;  // B*T
constexpr double TAU1d = 1.2231301601484298;  // exp(-1.5)+1
constexpr double TAU2d = 1.3678794411714423;  // exp(-1.0)+1  (== TAU4)
constexpr double TAU3d = 1.4493289641172216;  // exp(-0.8)+1

constexpr int LSTM_L = 32, LSTM_W = 96, LSTM_NCH = TT / LSTM_L;  // 1600
constexpr int HRL = 64;                  // hr-module output chunk length
constexpr int HR_NCH = TT / HRL;         // 800
constexpr int FB_L = 32, FB_W = 32, FB_NCH = 512 / FB_L;  // 16

// workspace layout (float offsets)
constexpr size_t OFF_PRE   = 0;         // 51200*40 (+320 over-read pad)
constexpr size_t OFF_HSEQ  = 2048320;   // 51200*10
constexpr size_t OFF_XIN2  = 3072000;   // 51200*20
constexpr size_t OFF_OUT2  = 4096000;   // 51200*10
constexpr size_t OFF_OUT3  = 4608320;   // 512*100*10
constexpr size_t OFF_FUSED = 5120320;   // 512*200
constexpr size_t OFF_STATS = 5222720;   // 512*2 doubles (8-byte aligned)
}  // namespace

__device__ __forceinline__ float rcp_nr(float d) {
  float r = __builtin_amdgcn_rcpf(d);
  return r * (2.0f - d * r);  // one Newton step: ~1ulp
}

// K1: pregate[(b*100+tt)*40+l] = sum_c x[b][c][tt]*wih[l][c] + bih[l]+bhh[l]
__global__ void __launch_bounds__(256) k_pregate(const float* __restrict__ x,
                                                 const float* __restrict__ wih,
                                                 const float* __restrict__ bih,
                                                 const float* __restrict__ bhh,
                                                 float* __restrict__ pre) {
  __shared__ __align__(16) float xs[6400];   // xs[c*100+tt]
  __shared__ __align__(16) float wT[2560];   // wT[c*40+l]
  __shared__ float bl[40];
  const int b = blockIdx.x;
  const int tid = threadIdx.x;
  for (int i = tid; i < 6400; i += 256) xs[i] = x[b * 6400 + i];  // coalesced
  for (int i = tid; i < 2560; i += 256) {
    const int c = i / 40;
    const int l = i - c * 40;
    wT[i] = wih[l * 64 + c];
  }
  if (tid < 40) bl[tid] = bih[tid] + bhh[tid];
  __syncthreads();
  if (tid >= 250) return;              // 25 tt-tiles x 10 l-tiles
  const int ttile = tid / 10;
  const int ltile = tid - ttile * 10;
  const int tt0 = ttile * 4;
  const int l0 = ltile * 4;
  float acc[4][4];
#pragma unroll
  for (int i = 0; i < 4; ++i)
#pragma unroll
    for (int j = 0; j < 4; ++j) acc[i][j] = bl[l0 + j];
#pragma unroll 8
  for (int c = 0; c < 64; ++c) {
    const float4 wv = *(const float4*)&wT[c * 40 + l0];
    const float4 xv = *(const float4*)&xs[c * 100 + tt0];
    const float xa[4] = {xv.x, xv.y, xv.z, xv.w};
    const float wa[4] = {wv.x, wv.y, wv.z, wv.w};
#pragma unroll
    for (int i = 0; i < 4; ++i)
#pragma unroll
      for (int j = 0; j < 4; ++j) acc[i][j] = fmaf(xa[i], wa[j], acc[i][j]);
  }
#pragma unroll
  for (int i = 0; i < 4; ++i) {
    float4 o;
    o.x = acc[i][0]; o.y = acc[i][1]; o.z = acc[i][2]; o.w = acc[i][3];
    *(float4*)&pre[(b * 100 + tt0 + i) * 40 + l0] = o;
  }
}

// K2: chunk-parallel LSTM (warm-up LSTM_W from (0,0) -> bit-exact merge).
__global__ void __launch_bounds__(64) k_lstm(const float* __restrict__ pre,
                                             const float* __restrict__ whh,
                                             float* __restrict__ hseq) {
  const int lane = threadIdx.x;
  const int l = lane < 40 ? lane : 0;
  float wh[10];
#pragma unroll
  for (int j = 0; j < 10; ++j) wh[j] = whh[l * 10 + j];
  const int jm = lane % 10;
  const bool is_g = (l >= 20) & (l < 30);
  const float sel = is_g ? 2.0f : -1.0f;
  const int outstart = blockIdx.x * LSTM_L;
  const int start = (outstart >= LSTM_W) ? outstart - LSTM_W : 0;  // mult of 32
  const int end = outstart + LSTM_L;
  float cst = 0.0f;
  float h[10];
#pragma unroll
  for (int j = 0; j < 10; ++j) h[j] = 0.0f;
  float pbuf[8];
#pragma unroll
  for (int i = 0; i < 8; ++i) pbuf[i] = pre[(start + i) * 40 + l];
#pragma unroll 8
  for (int t = start; t < end; ++t) {
    float g = pbuf[t & 7];
    pbuf[t & 7] = pre[(t + 8) * 40 + l];  // last chunk over-reads into pad
#pragma unroll
    for (int j = 0; j < 10; ++j) g = fmaf(h[j], wh[j], g);
    const float e = __expf(sel * g);
    const float r = rcp_nr(1.0f + e);
    const float act = is_g ? (1.0f - 2.0f * r) : r;
    const float ai = __shfl(act, jm);
    const float af = __shfl(act, jm + 10);
    const float ag = __shfl(act, jm + 20);
    const float ao = __shfl(act, jm + 30);
    cst = af * cst + ai * ag;
    const float hn = ao * (1.0f - 2.0f * rcp_nr(__expf(2.0f * cst) + 1.0f));
    if ((lane < 10) & (t >= outstart)) hseq[t * 10 + lane] = hn;
#pragma unroll
    for (int j = 0; j < 10; ++j)
      h[j] = __uint_as_float(__builtin_amdgcn_readlane(__float_as_uint(hn), j));
  }
}

// K3/K4: fused hr_module, 256 threads, weight rows cached in VGPRs.
template <int MODE, int O>
__global__ void __launch_bounds__(256) k_hr(const float* __restrict__ src,
                                            const float* __restrict__ sw,
                                            const float* __restrict__ sb,
                                            const float* __restrict__ cw,
                                            const float* __restrict__ cb,
                                            const float* __restrict__ fw,
                                            const float* __restrict__ fb,
                                            const float* __restrict__ skw,
                                            const float* __restrict__ skb,
                                            float* __restrict__ outp) {
  __shared__ __align__(16) float xin_s[128 * 20];
  __shared__ __align__(16) float hs_s[MODE == 0 ? 128 * 10 : 4];
  __shared__ __align__(16) float hl_s[96 * 60];   // also reused as P5 result
  __shared__ __align__(16) float c_s[96 * 20];
  __shared__ __align__(16) float s4_s[HRL * 20];
  __shared__ __align__(16) float cw_s[1200];
  __shared__ __align__(16) float fw_s[O * 20];
  __shared__ __align__(16) float skw_s[O * 20];
  __shared__ __align__(16) float sw_s[MODE == 0 ? 200 : 4];
  __shared__ float cb_s[20];
  __shared__ float fb_s[O];
  __shared__ float skb_s[O];
  __shared__ float sb_s[20];

  const int tid = threadIdx.x;
  const int outstart = blockIdx.x * HRL;
  const int end = outstart + HRL;
  const int s2 = (outstart >= 32) ? outstart - 32 : 0;
  const int s1 = (s2 >= 32) ? s2 - 32 : 0;
  const int n1 = end - s1;  // <=128, multiple of 32
  const int n2 = end - s2;  // <=96

  // ---- stage (float4) ----
  for (int i = tid; i < 300; i += 256)
    ((float4*)cw_s)[i] = ((const float4*)cw)[i];
  for (int i = tid; i < O * 5; i += 256) {
    ((float4*)fw_s)[i] = ((const float4*)fw)[i];
    ((float4*)skw_s)[i] = ((const float4*)skw)[i];
  }
  if (tid < O) { fb_s[tid] = fb[tid]; skb_s[tid] = skb[tid]; }
  if (tid >= 32 && tid < 52) cb_s[tid - 32] = cb[tid - 32];
  if (MODE == 0) {
    for (int i = tid; i < 50; i += 256)
      ((float4*)sw_s)[i] = ((const float4*)sw)[i];
    if (tid >= 64 && tid < 84) sb_s[tid - 64] = sb[tid - 64];
    const float4* gsrc = (const float4*)(src + (size_t)s1 * 10);
    for (int i = tid; i < n1 * 10 / 4; i += 256) ((float4*)hs_s)[i] = gsrc[i];
  } else {
    const float4* gsrc = (const float4*)(src + (size_t)s1 * 20);
    for (int i = tid; i < n1 * 5; i += 256) ((float4*)xin_s)[i] = gsrc[i];
  }
  __syncthreads();

  // ---- P1: sconv -> xin_s (MODE 0). thread=(o,rg), weights in regs ----
  if (MODE == 0) {
    const int rg = tid / 20;
    const int o = tid - rg * 20;
    if (rg < 12) {
      float2 w[5];
      const float* wp = sw_s + o * 10;
#pragma unroll
      for (int q = 0; q < 5; ++q) w[q] = *(const float2*)&wp[q * 2];
      const float bias = sb_s[o];
      for (int rel = rg; rel < n1; rel += 12) {
        const float* hp = hs_s + rel * 10;  // broadcast across the 20 o-lanes
        float acc = bias;
#pragma unroll
        for (int q = 0; q < 5; ++q) {
          const float2 h = *(const float2*)&hp[q * 2];
          acc = fmaf(h.x, w[q].x, acc);
          acc = fmaf(h.y, w[q].y, acc);
        }
        xin_s[rel * 20 + o] = acc;
      }
    }
    __syncthreads();
  }

  // ---- P2: lif3 scan (wave 0, 60 chains) ----
  if (tid < 64) {
    const int cid = tid < 60 ? tid : 0;
    const int f = cid / 3;
    const int k = cid - f * 3;
    const float tau = (k == 0) ? (float)TAU1d : (k == 1) ? (float)TAU2d : (float)TAU3d;
    const float rt = 1.0f / tau;
    const float th = (k == 0) ? 0.14f : (k == 1) ? 0.08f : 0.06f;
    float v = 0.0f;
#pragma unroll 8
    for (int t = s1; t < end; ++t) {
      const float x = xin_s[(t - s1) * 20 + f];
      v = fmaf(x - v, rt, v);
      const float sp = (v - th >= 0.0f) ? 1.0f : 0.0f;
      if ((tid < 60) & (t >= s2)) hl_s[(t - s2) * 60 + tid] = sp;
      v = (sp != 0.0f) ? 0.0f : v;
    }
  }
  __syncthreads();

  // ---- P3: conv60 -> c_s. thread=(o,rg), 15xfloat4 weights in regs ----
  {
    const int rg = tid / 20;
    const int o = tid - rg * 20;
    if (rg < 12) {
      float4 w[15];
      const float* wp = cw_s + o * 60;
#pragma unroll
      for (int q = 0; q < 15; ++q) w[q] = *(const float4*)&wp[q * 4];
      const float bias = cb_s[o];
      for (int rel = rg; rel < n2; rel += 12) {
        const float* hp = hl_s + rel * 60;  // broadcast across the 20 o-lanes
        float acc = bias;
#pragma unroll
        for (int q = 0; q < 15; ++q) {
          const float4 h = *(const float4*)&hp[q * 4];
          acc = fmaf(h.x, w[q].x, acc);
          acc = fmaf(h.y, w[q].y, acc);
          acc = fmaf(h.z, w[q].z, acc);
          acc = fmaf(h.w, w[q].w, acc);
        }
        c_s[rel * 20 + o] = acc;
      }
    }
  }
  __syncthreads();

  // ---- P4: lifseq scan (wave 0, 20 chains) ----
  if (tid < 64) {
    const int f = tid < 20 ? tid : 0;
    const float rt = 1.0f / (float)TAU2d;
    float v = 0.0f;
#pragma unroll 8
    for (int t = s2; t < end; ++t) {
      const float x = c_s[(t - s2) * 20 + f];
      v = fmaf(x - v, rt, v);
      const float sp = (v - 0.08f >= 0.0f) ? 1.0f : 0.0f;
      if ((tid < 20) & (t >= outstart)) s4_s[(t - outstart) * 20 + tid] = sp;
      v = (sp != 0.0f) ? 0.0f : v;
    }
  }
  __syncthreads();

  // ---- P5: fcskip -> LDS result (hl_s reused), then coalesced global ----
  float* res = hl_s;  // HRL*O <= 1280 floats, hl_s is dead after P3
  {
    constexpr int ORG = (O == 20) ? 12 : 25;
    const int rg = tid / O;
    const int o = tid - rg * O;
    const int xoff = outstart - s1;
    if (rg < ORG) {
      float4 fv[5], kv[5];
      const float* fwp = fw_s + o * 20;
      const float* swp = skw_s + o * 20;
#pragma unroll
      for (int q = 0; q < 5; ++q) {
        fv[q] = *(const float4*)&fwp[q * 4];
        kv[q] = *(const float4*)&swp[q * 4];
      }
      const float bias = fb_s[o] + skb_s[o];
      for (int rel = rg; rel < HRL; rel += ORG) {
        const float* s = s4_s + rel * 20;            // broadcast rows
        const float* xi = xin_s + (xoff + rel) * 20; // broadcast rows
        float acc = bias;
#pragma unroll
        for (int q = 0; q < 5; ++q) {
          const float4 sv = *(const float4*)&s[q * 4];
          const float4 xv = *(const float4*)&xi[q * 4];
          acc = fmaf(sv.x, fv[q].x, fmaf(xv.x, kv[q].x, acc));
          acc = fmaf(sv.y, fv[q].y, fmaf(xv.y, kv[q].y, acc));
          acc = fmaf(sv.z, fv[q].z, fmaf(xv.z, kv[q].z, acc));
          acc = fmaf(sv.w, fv[q].w, fmaf(xv.w, kv[q].w, acc));
        }
        res[rel * O + o] = acc;
      }
    }
  }
  __syncthreads();
  {
    float4* gout = (float4*)(outp + (size_t)outstart * O);
    for (int i = tid; i < HRL * O / 4; i += 256) gout[i] = ((float4*)res)[i];
  }
}

// K5: final LIF over batch axis: 1000 chains, chunked over b (L=W=32).
__global__ void __launch_bounds__(256) k_flif(const float* __restrict__ out2,
                                              float* __restrict__ out3) {
  const int idx = blockIdx.x * 256 + threadIdx.x;
  if (idx >= FB_NCH * 1000) return;
  const int chunk = idx / 1000;
  const int chain = idx - chunk * 1000;
  const float rt = 1.0f / (float)TAU2d;
  const int outstart = chunk * FB_L;
  const int start = (outstart >= FB_W) ? outstart - FB_W : 0;
  const int end = outstart + FB_L;
  float v = 0.0f;
  float xb[4];
#pragma unroll
  for (int i = 0; i < 4; ++i) xb[i] = out2[(start + i) * 1000 + chain];
#pragma unroll 4
  for (int b = start; b < end; ++b) {
    const float x = xb[b & 3];
    xb[b & 3] = out2[(b + 4) * 1000 + chain];  // over-read harmless (unused)
    v = fmaf(x - v, rt, v);
    const float sp = (v - 0.08f >= 0.0f) ? 1.0f : 0.0f;
    if (b >= outstart) out3[b * 1000 + chain] = sp;
    v = (sp != 0.0f) ? 0.0f : v;
  }
}

// K6: dp -> avg -> fused; per-block (per-b) partial sum/sumsq in double.
__global__ void __launch_bounds__(256) k_fused(const float* __restrict__ out3,
                                               float* __restrict__ fused,
                                               double* __restrict__ stats) {
  __shared__ float dp_s[200];
  __shared__ float avg_s[20];
  __shared__ double red_s[8];
  const int b = blockIdx.x;
  const int tid = threadIdx.x;
  if (tid < 200) {
    const int f = tid / 20;
    const int seg = tid - f * 20;
    const float* base = out3 + b * 1000 + seg * 50 + f;
    dp_s[tid] = ((base[30] + base[40]) - (base[0] + base[10])) * 0.5f;
  }
  __syncthreads();
  if (tid < 20) {
    float s = 0.0f;
#pragma unroll
    for (int f = 0; f < 10; ++f) s += dp_s[f * 20 + tid];
    avg_s[tid] = s / 10.0f;
  }
  __syncthreads();
  float val = 0.0f;
  if (tid < 200) {
    val = dp_s[tid] * avg_s[tid % 20];
    fused[b * 200 + tid] = val;
  }
  double sv = (double)val, sq = (double)val * (double)val;
#pragma unroll
  for (int off = 32; off > 0; off >>= 1) {
    sv += __shfl_down(sv, off);
    sq += __shfl_down(sq, off);
  }
  const int wid = tid >> 6;
  if ((tid & 63) == 0) { red_s[wid * 2] = sv; red_s[wid * 2 + 1] = sq; }
  __syncthreads();
  if (tid == 0) {
    double S = 0.0, Q = 0.0;
#pragma unroll
    for (int w = 0; w < 4; ++w) { S += red_s[w * 2]; Q += red_s[w * 2 + 1]; }
    stats[b * 2] = S;
    stats[b * 2 + 1] = Q;
  }
}

// K7: reduce stats -> mean/var -> bn -> logits -> log_softmax. One block.
__global__ void __launch_bounds__(1024) k_head(const float* __restrict__ fused,
                                               const double* __restrict__ stats,
                                               const float* __restrict__ gamma,
                                               const float* __restrict__ beta,
                                               const float* __restrict__ clsw,
                                               const float* __restrict__ clsb,
                                               float* __restrict__ out) {
  __shared__ double redS[16], redQ[16];
  __shared__ float cls_s[600];
  __shared__ float cb_s[3];
  __shared__ float mr_s[2];
  const int tid = threadIdx.x;
  if (tid < 600) cls_s[tid] = clsw[tid];
  if (tid < 3) cb_s[tid] = clsb[tid];
  double s = 0.0, q = 0.0;
  if (tid < 512) { s = stats[2 * tid]; q = stats[2 * tid + 1]; }
#pragma unroll
  for (int off = 32; off > 0; off >>= 1) {
    s += __shfl_down(s, off);
    q += __shfl_down(q, off);
  }
  const int wid = tid >> 6;
  if ((tid & 63) == 0) { redS[wid] = s; redQ[wid] = q; }
  __syncthreads();
  if (tid == 0) {
    double S = 0.0, Q = 0.0;
#pragma unroll
    for (int w = 0; w < 16; ++w) { S += redS[w]; Q += redQ[w]; }
    const double mean = S / 102400.0;
    const double var = Q / 102400.0 - mean * mean;
    mr_s[0] = (float)mean;
    mr_s[1] = (float)(1.0 / sqrt(var + 1e-5));
  }
  __syncthreads();
  if (tid < 512) {
    const float mean = mr_s[0], rsig = mr_s[1];
    const float ga = gamma[0], be = beta[0];
    const float* fr = fused + tid * 200;
    float l0 = cb_s[0], l1 = cb_s[1], l2 = cb_s[2];
    for (int j = 0; j < 200; ++j) {
      const float bn = (fr[j] - mean) * rsig * ga + be;
      l0 = fmaf(bn, cls_s[j], l0);
      l1 = fmaf(bn, cls_s[200 + j], l1);
      l2 = fmaf(bn, cls_s[400 + j], l2);
    }
    const float m = fmaxf(l0, fmaxf(l1, l2));
    const float lse = m + logf(expf(l0 - m) + expf(l1 - m) + expf(l2 - m));
    out[tid * 3 + 0] = l0 - lse;
    out[tid * 3 + 1] = l1 - lse;
    out[tid * 3 + 2] = l2 - lse;
  }
}

extern "C" void kernel_launch(void* const* d_in, const int* in_sizes, int n_in,
                              void* d_out, int out_size, void* d_ws, size_t ws_size,
                              hipStream_t stream) {
  (void)in_sizes; (void)n_in; (void)out_size; (void)ws_size;
  const float* x     = (const float*)d_in[0];
  const float* wih   = (const float*)d_in[1];
  const float* whh   = (const float*)d_in[2];
  const float* bih   = (const float*)d_in[3];
  const float* bhh   = (const float*)d_in[4];
  const float* sc_w  = (const float*)d_in[5];
  const float* sc_b  = (const float*)d_in[6];
  const float* c1w   = (const float*)d_in[7];
  const float* c1b   = (const float*)d_in[8];
  const float* f1w   = (const float*)d_in[9];
  const float* f1b   = (const float*)d_in[10];
  const float* k1w   = (const float*)d_in[11];
  const float* k1b   = (const float*)d_in[12];
  const float* c2w   = (const float*)d_in[13];
  const float* c2b   = (const float*)d_in[14];
  const float* f2w   = (const float*)d_in[15];
  const float* f2b   = (const float*)d_in[16];
  const float* k2w   = (const float*)d_in[17];
  const float* k2b   = (const float*)d_in[18];
  const float* gamma = (const float*)d_in[19];
  const float* beta  = (const float*)d_in[20];
  const float* clsw  = (const float*)d_in[21];
  const float* clsb  = (const float*)d_in[22];
  float* out = (float*)d_out;
  float* ws = (float*)d_ws;

  float* pre   = ws + OFF_PRE;
  float* hseq  = ws + OFF_HSEQ;
  float* xin2  = ws + OFF_XIN2;
  float* out2  = ws + OFF_OUT2;
  float* out3  = ws + OFF_OUT3;
  float* fused = ws + OFF_FUSED;
  double* stats = (double*)(ws + OFF_STATS);

  k_pregate<<<512, 256, 0, stream>>>(x, wih, bih, bhh, pre);
  k_lstm<<<LSTM_NCH, 64, 0, stream>>>(pre, whh, hseq);
  k_hr<0, 20><<<HR_NCH, 256, 0, stream>>>(hseq, sc_w, sc_b, c1w, c1b, f1w, f1b,
                                          k1w, k1b, xin2);
  k_hr<1, 10><<<HR_NCH, 256, 0, stream>>>(xin2, nullptr, nullptr, c2w, c2b,
                                          f2w, f2b, k2w, k2b, out2);
  k_flif<<<(FB_NCH * 1000 + 255) / 256, 256, 0, stream>>>(out2, out3);
  k_fused<<<512, 256, 0, stream>>>(out3, fused, stats);
  k_head<<<1, 1024, 0, stream>>>(fused, stats, gamma, beta, clsw, clsb, out);
}